// Round 11
// baseline (260.255 us; speedup 1.0000x reference)
//
#include <hip/hip_runtime.h>
#include <hip/hip_bf16.h>

typedef __attribute__((ext_vector_type(8))) short bf16x8;
typedef __attribute__((ext_vector_type(4))) float f32x4;
typedef __attribute__((ext_vector_type(4))) short short4v;

__device__ __forceinline__ unsigned short f2bf(float f) {
  union { float f; unsigned u; } x; x.f = f;
  return (unsigned short)((x.u + 0x7FFFu + ((x.u >> 16) & 1u)) >> 16);
}

__device__ __forceinline__ short f2bf_hw(float f) {
  __hip_bfloat16 h = __float2bfloat16(f);
  return *(short*)&h;
}

__device__ __forceinline__ void lds_cp16(const void* g, void* l) {
  __builtin_amdgcn_global_load_lds(
      (const __attribute__((address_space(1))) void*)g,
      (__attribute__((address_space(3))) void*)l,
      16, 0, 0);
}

#define GBAR() do { __builtin_amdgcn_s_barrier(); __builtin_amdgcn_sched_barrier(0); } while (0)

// ---------------- cast fp32 -> bf16, vectorized ----------------
__global__ __launch_bounds__(256) void cast_x(const float* __restrict__ in,
                                              short* __restrict__ out, int n4) {
  int i = blockIdx.x * 256 + threadIdx.x;
  if (i >= n4) return;
  float4 v = reinterpret_cast<const float4*>(in)[i];
  short4v o;
  o.x = (short)f2bf(v.x); o.y = (short)f2bf(v.y);
  o.z = (short)f2bf(v.z); o.w = (short)f2bf(v.w);
  reinterpret_cast<short4v*>(out)[i] = o;
}

// ---------------- transpose + cast: in KxN fp32 -> out NxK bf16 ----------------
__global__ __launch_bounds__(256) void transp_cast(const float* __restrict__ in,
                                                   short* __restrict__ out,
                                                   int K, int N) {
  __shared__ float t[32][33];
  int bn = blockIdx.x * 32, bk = blockIdx.y * 32;
  int tx = threadIdx.x, ty = threadIdx.y;
  for (int i = ty; i < 32; i += 8)
    t[i][tx] = in[(size_t)(bk + i) * N + bn + tx];
  __syncthreads();
  for (int i = ty; i < 32; i += 8)
    out[(size_t)(bn + i) * K + bk + tx] = (short)f2bf(t[tx][i]);
}

// ---------------- fused Wq/Wk/Wv transpose+cast into Wqkv (NxK, N=3072) -----
__global__ __launch_bounds__(256) void transp_qkv(const float* __restrict__ Wq,
                                                  const float* __restrict__ Wk,
                                                  const float* __restrict__ Wv,
                                                  short* __restrict__ out) {
  __shared__ float t[32][33];
  const int K = 2048;
  int bnG = blockIdx.x * 32;           // output row (= weight col) base, [0,3072)
  int bk = blockIdx.y * 32;
  const float* src; int N, bn;
  if (bnG < 2048)      { src = Wq; N = 2048; bn = bnG; }
  else if (bnG < 2560) { src = Wk; N = 512;  bn = bnG - 2048; }
  else                 { src = Wv; N = 512;  bn = bnG - 2560; }
  int tx = threadIdx.x, ty = threadIdx.y;
  for (int i = ty; i < 32; i += 8)
    t[i][tx] = src[(size_t)(bk + i) * N + bn + tx];
  __syncthreads();
  for (int i = ty; i < 32; i += 8)
    out[(size_t)(bnG + i) * K + bk + tx] = (short)f2bf(t[tx][i]);
}

// ---------------- bf16 transpose: per head [2048 pos][128 dh] -> [128 dh][2048 pos]
__global__ __launch_bounds__(256) void transp_v(const short* __restrict__ V,
                                                short* __restrict__ VTo) {
  __shared__ short t[32][34];
  const int hd = blockIdx.z;
  const int p0 = blockIdx.x * 32, d0 = blockIdx.y * 32;
  const short* src = V + (size_t)hd * 2048 * 128;
  short* dst = VTo + (size_t)hd * 2048 * 128;
  int tx = threadIdx.x, ty = threadIdx.y;
  for (int i = ty; i < 32; i += 8)
    t[i][tx] = src[(size_t)(p0 + i) * 128 + d0 + tx];
  __syncthreads();
  for (int i = ty; i < 32; i += 8)
    dst[(size_t)(d0 + i) * 2048 + p0 + tx] = t[tx][i];
}

// ---------------- 8-wave deep-phase GEMM (unchanged) ------------
template <int BM, int EPI>
__global__ __launch_bounds__(512, 2) void gemm8p(
    const short* __restrict__ A, const short* __restrict__ Bt,
    float* __restrict__ C,
    short* __restrict__ Qo, short* __restrict__ Ko, short* __restrict__ Vo,
    const float* __restrict__ cosT, const float* __restrict__ sinT,
    int N, int Kd, int nbm) {
  constexpr int NM = BM / 64;
  __shared__ __align__(16) short As[2][BM * 64];
  __shared__ __align__(16) short Bs[2][256 * 64];
  const int tid = threadIdx.x;
  const int l = tid & 63, l15 = l & 15, l4 = l >> 4;
  const int wid = tid >> 6, wr = wid >> 1, wc = wid & 1;
  const int cpx = gridDim.x >> 3;
  const int sid = (blockIdx.x & 7) * cpx + (blockIdx.x >> 3);
  const int bm = sid % nbm, bn = sid / nbm;

  const int srow = tid >> 3;
  const int sch = tid & 7;

  auto stA = [&](int dbuf, int k0, int i) {
    const int rl = srow + i * 64;
    const int c = sch ^ (rl & 7);
    lds_cp16(A + (size_t)(bm * BM + rl) * Kd + k0 + c * 8,
             (char*)As[dbuf] + tid * 16 + i * 8192);
  };
  auto stB = [&](int dbuf, int k0, int j) {
    const int rl = srow + j * 64;
    const int c = sch ^ (rl & 7);
    lds_cp16(Bt + (size_t)(bn * 256 + rl) * Kd + k0 + c * 8,
             (char*)Bs[dbuf] + tid * 16 + j * 8192);
  };
  auto rdA = [&](int dbuf, int m, int kb) {
    const int row = wr * (BM / 4) + m * 16 + l15;
    return *(const bf16x8*)((const char*)As[dbuf] + (row << 7) +
                            ((kb * 64 + l4 * 16) ^ ((row & 7) << 4)));
  };
  auto rdB = [&](int dbuf, int nh, int f, int kb) {
    const int row = wc * 128 + nh * 64 + f * 16 + l15;
    return *(const bf16x8*)((const char*)Bs[dbuf] + (row << 7) +
                            ((kb * 64 + l4 * 16) ^ ((row & 7) << 4)));
  };

  f32x4 acc[NM][8];
#pragma unroll
  for (int m = 0; m < NM; m++)
#pragma unroll
    for (int n = 0; n < 8; n++) acc[m][n] = (f32x4){0.f, 0.f, 0.f, 0.f};

  const int NT = Kd >> 6;

#pragma unroll
  for (int i = 0; i < NM; i++) stA(0, 0, i);
#pragma unroll
  for (int j = 0; j < 4; j++) stB(0, 0, j);
  asm volatile("s_waitcnt vmcnt(0)" ::: "memory");
  GBAR();

  for (int kt = 0; kt < NT; kt++) {
    const int buf = kt & 1, nbf = buf ^ 1;
    const bool stg = (kt + 1 < NT);
    const int k1 = (kt + 1) << 6;
    bf16x8 a[NM], b[4];

    // ---------- phase 0 ----------
#pragma unroll
    for (int m = 0; m < NM; m++) a[m] = rdA(buf, m, 0);
#pragma unroll
    for (int f = 0; f < 4; f++) b[f] = rdB(buf, 0, f, 0);
    if (stg) { stA(nbf, k1, 0); stA(nbf, k1, 1); }
    if (stg) asm volatile("s_waitcnt vmcnt(2)" ::: "memory");
    else     asm volatile("s_waitcnt vmcnt(0)" ::: "memory");
    GBAR();
    asm volatile("s_waitcnt lgkmcnt(0)" ::: "memory");
    __builtin_amdgcn_sched_barrier(0);
    __builtin_amdgcn_s_setprio(1);
#pragma unroll
    for (int m = 0; m < NM; m++)
#pragma unroll
      for (int f = 0; f < 4; f++)
        acc[m][f] = __builtin_amdgcn_mfma_f32_16x16x32_bf16(a[m], b[f], acc[m][f], 0, 0, 0);
    __builtin_amdgcn_s_setprio(0);
    GBAR();

    // ---------- phase 1 ----------
#pragma unroll
    for (int f = 0; f < 4; f++) b[f] = rdB(buf, 1, f, 0);
    if (stg) {
      if (BM == 256) { stA(nbf, k1, 2); stA(nbf, k1, 3); }
      else           { stB(nbf, k1, 0); stB(nbf, k1, 2); }
    }
    GBAR();
    asm volatile("s_waitcnt lgkmcnt(0)" ::: "memory");
    __builtin_amdgcn_sched_barrier(0);
    __builtin_amdgcn_s_setprio(1);
#pragma unroll
    for (int m = 0; m < NM; m++)
#pragma unroll
      for (int f = 0; f < 4; f++)
        acc[m][4 + f] = __builtin_amdgcn_mfma_f32_16x16x32_bf16(a[m], b[f], acc[m][4 + f], 0, 0, 0);
    __builtin_amdgcn_s_setprio(0);
    GBAR();

    // ---------- phase 2 ----------
#pragma unroll
    for (int m = 0; m < NM; m++) a[m] = rdA(buf, m, 1);
#pragma unroll
    for (int f = 0; f < 4; f++) b[f] = rdB(buf, 0, f, 1);
    if (stg) {
      if (BM == 256) { stB(nbf, k1, 0); stB(nbf, k1, 2); }
      else           { stB(nbf, k1, 1); stB(nbf, k1, 3); }
    }
    GBAR();
    asm volatile("s_waitcnt lgkmcnt(0)" ::: "memory");
    __builtin_amdgcn_sched_barrier(0);
    __builtin_amdgcn_s_setprio(1);
#pragma unroll
    for (int m = 0; m < NM; m++)
#pragma unroll
      for (int f = 0; f < 4; f++)
        acc[m][f] = __builtin_amdgcn_mfma_f32_16x16x32_bf16(a[m], b[f], acc[m][f], 0, 0, 0);
    __builtin_amdgcn_s_setprio(0);
    GBAR();

    // ---------- phase 3 ----------
#pragma unroll
    for (int f = 0; f < 4; f++) b[f] = rdB(buf, 1, f, 1);
    if (stg && BM == 256) { stB(nbf, k1, 1); stB(nbf, k1, 3); }
    if (stg) asm volatile("s_waitcnt vmcnt(2)" ::: "memory");
    GBAR();
    asm volatile("s_waitcnt lgkmcnt(0)" ::: "memory");
    __builtin_amdgcn_sched_barrier(0);
    __builtin_amdgcn_s_setprio(1);
#pragma unroll
    for (int m = 0; m < NM; m++)
#pragma unroll
      for (int f = 0; f < 4; f++)
        acc[m][4 + f] = __builtin_amdgcn_mfma_f32_16x16x32_bf16(a[m], b[f], acc[m][4 + f], 0, 0, 0);
    __builtin_amdgcn_s_setprio(0);
    GBAR();
  }

  if (EPI == 0) {
#pragma unroll
    for (int m = 0; m < NM; m++) {
      const int grow = bm * BM + wr * (BM / 4) + m * 16 + l4 * 4;
#pragma unroll
      for (int ni = 0; ni < 8; ni++) {
        const int col = bn * 256 + wc * 128 + (ni >> 2) * 64 + (ni & 3) * 16 + l15;
#pragma unroll
        for (int r = 0; r < 4; r++)
          C[(size_t)(grow + r) * N + col] = acc[m][ni][r];
      }
    }
  } else {
    const int head = bn * 2 + wc;
#pragma unroll
    for (int m = 0; m < NM; m++) {
#pragma unroll
      for (int r = 0; r < 4; r++) {
        const int grow = bm * BM + wr * (BM / 4) + m * 16 + l4 * 4 + r;
        const int bb = grow >> 11, pos = grow & 2047;
        if (head < 20) {
          float c4[4], s4[4];
#pragma unroll
          for (int ni = 0; ni < 4; ni++) {
            const int dh = ni * 16 + l15;
            c4[ni] = cosT[pos * 128 + dh];
            s4[ni] = sinT[pos * 128 + dh];
          }
          short* dst;
          if (head < 16) dst = Qo + ((size_t)(bb * 16 + head) * 2048 + pos) * 128;
          else           dst = Ko + ((size_t)(bb * 4 + (head - 16)) * 2048 + pos) * 128;
#pragma unroll
          for (int ni = 0; ni < 4; ni++) {
            const int dh = ni * 16 + l15;
            float xlo = acc[m][ni][r], xhi = acc[m][ni + 4][r];
            dst[dh]      = (short)f2bf(xlo * c4[ni] - xhi * s4[ni]);
            dst[dh + 64] = (short)f2bf(xhi * c4[ni] + xlo * s4[ni]);
          }
        } else {
          short* dst = Vo + ((size_t)(bb * 4 + (head - 20)) * 2048 + pos) * 128;
#pragma unroll
          for (int ni = 0; ni < 8; ni++)
            dst[(ni >> 2) * 64 + (ni & 3) * 16 + l15] = (short)f2bf(acc[m][ni][r]);
        }
      }
    }
  }
}

// ---------------- flash attention, causal, GQA — 8-wave 128-row blocks ------
// 512 blocks x 512 thr (8 waves x 16 q-rows = 128 q-rows per pass). Block
// owns the UNIFORM q-range pair (pp, 15-pp) of 128 rows each: 34 kv-tiles.
// LDS 80KB -> 2 blocks/CU x 8 waves = 16 waves/CU (4/SIMD, VGPR<=128).
// Per-wave code identical to the round-7 verified kernel: KVBLK=64 staged
// dbuf K/V^T via global_load_lds (pre-swizzled src, XOR (row&7)<<4), no-max
// softmax, l via ones-MFMA. XCD chunking: bid%8 -> 4-bh chunk.
__global__ __launch_bounds__(512, 4) void attn_fwd(
    const short* __restrict__ Q, const short* __restrict__ K,
    const short* __restrict__ VT, short* __restrict__ AO) {
  __shared__ __align__(16) short Ks[2][64 * 128];
  __shared__ __align__(16) short VTs[2][128 * 64];
  __shared__ __align__(16) short Pl[8][16 * 64];
  const int tid = threadIdx.x;
  const int w = tid >> 6, l = tid & 63;
  const int l15 = l & 15, l4 = l >> 4;
  const int bid = blockIdx.x;
  const int lg = (bid & 7) * 64 + (bid >> 3);   // XCD-chunked logical id
  const int bh = lg >> 4, pp = lg & 15;         // 16 q-range pairs per bh
  const int b = bh >> 4, h = bh & 15, kv = h >> 2;
  const short* Qbase = Q + (size_t)(b * 16 + h) * 2048 * 128;
  const short* Kbase = K + (size_t)(b * 4 + kv) * 2048 * 128;
  const short* VTb   = VT + (size_t)(b * 4 + kv) * 2048 * 128;

  // staging (512 thr, 2 cp16 each for K and V^T), pre-swizzled source chunk
  int rk[2], ck[2], dv[2], kc[2];
#pragma unroll
  for (int i = 0; i < 2; i++) {
    const int c = tid + i * 512;
    rk[i] = c >> 4; ck[i] = (c & 15) ^ (rk[i] & 7);
    dv[i] = c >> 3; kc[i] = (c & 7) ^ (dv[i] & 7);
  }

  const float SCL = 0.08838834764831845f * 1.4426950408889634f;  // 1/sqrt(128)*log2e

  bf16x8 ones;
#pragma unroll
  for (int j = 0; j < 8; j++) ones[j] = (short)0x3F80;

  for (int qq = 0; qq < 2; qq++) {
    const int qr = qq ? (15 - pp) : pp;       // 128-row q-range index
    const int q0w = qr * 128 + w * 16;

    bf16x8 qf[4];
#pragma unroll
    for (int kb = 0; kb < 4; kb++)
      qf[kb] = *(const bf16x8*)(Qbase + (size_t)(q0w + l15) * 128 + kb * 32 + l4 * 8);

    f32x4 oacc[8];
#pragma unroll
    for (int i = 0; i < 8; i++) oacc[i] = (f32x4){0.f, 0.f, 0.f, 0.f};
    f32x4 lacc = (f32x4){0.f, 0.f, 0.f, 0.f};

    const int ntiles = 2 * qr + 2;

    __syncthreads();  // prior pass's LDS reads done before restaging
#pragma unroll
    for (int i = 0; i < 2; i++) {
      lds_cp16(Kbase + rk[i] * 128 + ck[i] * 8, (char*)Ks[0] + i * 8192 + tid * 16);
      lds_cp16(VTb + (size_t)dv[i] * 2048 + kc[i] * 8, (char*)VTs[0] + i * 8192 + tid * 16);
    }

    for (int nt = 0; nt < ntiles; nt++) {
      const int k0 = nt * 64, buf = nt & 1;
      __syncthreads();  // drains own vmcnt -> tile nt resident for all waves
      if (nt + 1 < ntiles) {
        const int kn = k0 + 64, bnx = buf ^ 1;
#pragma unroll
        for (int i = 0; i < 2; i++) {
          lds_cp16(Kbase + (size_t)(kn + rk[i]) * 128 + ck[i] * 8,
                   (char*)Ks[bnx] + i * 8192 + tid * 16);
          lds_cp16(VTb + (size_t)dv[i] * 2048 + kn + kc[i] * 8,
                   (char*)VTs[bnx] + i * 8192 + tid * 16);
        }
      }

      if (k0 <= q0w + 15) {  // skip fully-masked tiles for this wave
        // S = Q @ K^T : 16 q-rows x 64 keys per wave
        f32x4 sa[4];
#pragma unroll
        for (int kg = 0; kg < 4; kg++) sa[kg] = (f32x4){0.f, 0.f, 0.f, 0.f};
        __builtin_amdgcn_s_setprio(1);
#pragma unroll
        for (int kg = 0; kg < 4; kg++) {
          const int row = kg * 16 + l15;
          const int swz = (row & 7) << 4;
#pragma unroll
          for (int kb = 0; kb < 4; kb++) {
            const char* kp = (const char*)Ks[buf] + row * 256 + ((kb * 64 + l4 * 16) ^ swz);
            sa[kg] = __builtin_amdgcn_mfma_f32_16x16x32_bf16(qf[kb], *(const bf16x8*)kp, sa[kg], 0, 0, 0);
          }
        }
        __builtin_amdgcn_s_setprio(0);

        // P = exp(s*scale); mask only the diagonal tile
        float p[4][4];
        const bool domask = (k0 + 63 > q0w);
#pragma unroll
        for (int kg = 0; kg < 4; kg++)
#pragma unroll
          for (int r = 0; r < 4; r++) {
            float pv = exp2f(sa[kg][r] * SCL);
            if (domask) {
              int qrow = q0w + l4 * 4 + r;
              if (k0 + kg * 16 + l15 > qrow) pv = 0.f;
            }
            p[kg][r] = pv;
          }

        // P: C-layout -> A-layout via per-wave swizzled LDS
#pragma unroll
        for (int r = 0; r < 4; r++) {
          const int rw = l4 * 4 + r;
          const int swz = (rw & 7) << 4;
#pragma unroll
          for (int kg = 0; kg < 4; kg++)
            *(short*)((char*)Pl[w] + (rw * 128 + ((kg * 32 + l15 * 2) ^ swz))) =
                f2bf_hw(p[kg][r]);
        }
        asm volatile("s_waitcnt lgkmcnt(0)" ::: "memory");
        bf16x8 pf[2];
#pragma unroll
        for (int ks = 0; ks < 2; ks++)
          pf[ks] = *(const bf16x8*)((const char*)Pl[w] +
                   (l15 * 128 + ((ks * 64 + l4 * 16) ^ ((l15 & 7) << 4))));

        // O += P @ V^T ; l += P @ ones
        __builtin_amdgcn_s_setprio(1);
#pragma unroll
        for (int nb = 0; nb < 8; nb++) {
          const int d = nb * 16 + l15;
          const int dsw = (d & 7) << 4;
#pragma unroll
          for (int ks = 0; ks < 2; ks++) {
            const char* vp = (const char*)VTs[buf] + d * 128 + ((ks * 64 + l4 * 16) ^ dsw);
            oacc[nb] = __builtin_amdgcn_mfma_f32_16x16x32_bf16(pf[ks], *(const bf16x8*)vp, oacc[nb], 0, 0, 0);
          }
        }
        lacc = __builtin_amdgcn_mfma_f32_16x16x32_bf16(pf[0], ones, lacc, 0, 0, 0);
        lacc = __builtin_amdgcn_mfma_f32_16x16x32_bf16(pf[1], ones, lacc, 0, 0, 0);
        __builtin_amdgcn_s_setprio(0);
      }
    }

    // epilogue: normalize by l, write bf16 AO [B][L][H*Dh]
#pragma unroll
    for (int r = 0; r < 4; r++) {
      float inv = 1.0f / lacc[r];
      size_t rowb = ((size_t)b * 2048 + q0w + l4 * 4 + r) * 2048 + h * 128;
#pragma unroll
      for (int nb = 0; nb < 8; nb++)
        AO[rowb + nb * 16 + l15] = f2bf_hw(oacc[nb][r] * inv);
    }
  }
}

extern "C" void kernel_launch(void* const* d_in, const int* in_sizes, int n_in,
                              void* d_out, int out_size, void* d_ws, size_t ws_size,
                              hipStream_t stream) {
  const float* hs   = (const float*)d_in[0];
  const float* cosT = (const float*)d_in[1];
  const float* sinT = (const float*)d_in[2];
  const float* Wq   = (const float*)d_in[3];
  const float* Wk   = (const float*)d_in[4];
  const float* Wv   = (const float*)d_in[5];
  const float* Wo   = (const float*)d_in[6];
  float* out = (float*)d_out;

  char* p = (char*)d_ws;
  short* Xb   = (short*)p; p += (size_t)4096 * 2048 * 2;   // reused as AO
  short* Wqkv = (short*)p; p += (size_t)3072 * 2048 * 2;
  short* Wot  = (short*)p; p += (size_t)2048 * 2048 * 2;
  short* Qb   = (short*)p; p += (size_t)2 * 16 * 2048 * 128 * 2;
  short* Kb   = (short*)p; p += (size_t)2 * 4 * 2048 * 128 * 2;
  short* Vb   = (short*)p; p += (size_t)2 * 4 * 2048 * 128 * 2;
  short* VTb  = (short*)p; p += (size_t)2 * 4 * 2048 * 128 * 2;
  short* AO   = Xb;

  cast_x<<<8192, 256, 0, stream>>>(hs, Xb, 2097152);
  transp_qkv<<<dim3(96, 64), dim3(32, 8), 0, stream>>>(Wq, Wk, Wv, Wqkv);
  transp_cast<<<dim3(64, 64), dim3(32, 8), 0, stream>>>(Wo, Wot, 2048, 2048);

  // QKV: M=4096, N=3072 -> 192 blocks, fused RoPE epilogue
  gemm8p<256, 1><<<192, 512, 0, stream>>>(Xb, Wqkv, nullptr, Qb, Kb, Vb,
                                          cosT, sinT, 3072, 2048, 16);
  transp_v<<<dim3(64, 4, 8), dim3(32, 8), 0, stream>>>(Vb, VTb);
  attn_fwd<<<512, 512, 0, stream>>>(Qb, Kb, VTb, AO);
  // out-proj: M=4096, N=2048 -> 256 blocks
  gemm8p<128, 0><<<256, 512, 0, stream>>>(AO, Wot, out, nullptr, nullptr, nullptr,
                                          nullptr, nullptr, 2048, 2048, 32);
}

// Round 12
// 237.760 us; speedup vs baseline: 1.0946x; 1.0946x over previous
//
#include <hip/hip_runtime.h>
#include <hip/hip_bf16.h>

typedef __attribute__((ext_vector_type(8))) short bf16x8;
typedef __attribute__((ext_vector_type(4))) float f32x4;
typedef __attribute__((ext_vector_type(4))) short short4v;

__device__ __forceinline__ unsigned short f2bf(float f) {
  union { float f; unsigned u; } x; x.f = f;
  return (unsigned short)((x.u + 0x7FFFu + ((x.u >> 16) & 1u)) >> 16);
}

__device__ __forceinline__ short f2bf_hw(float f) {
  __hip_bfloat16 h = __float2bfloat16(f);
  return *(short*)&h;
}

__device__ __forceinline__ void lds_cp16(const void* g, void* l) {
  __builtin_amdgcn_global_load_lds(
      (const __attribute__((address_space(1))) void*)g,
      (__attribute__((address_space(3))) void*)l,
      16, 0, 0);
}

#define GBAR() do { __builtin_amdgcn_s_barrier(); __builtin_amdgcn_sched_barrier(0); } while (0)

// ---------------- cast fp32 -> bf16, vectorized ----------------
__global__ __launch_bounds__(256) void cast_x(const float* __restrict__ in,
                                              short* __restrict__ out, int n4) {
  int i = blockIdx.x * 256 + threadIdx.x;
  if (i >= n4) return;
  float4 v = reinterpret_cast<const float4*>(in)[i];
  short4v o;
  o.x = (short)f2bf(v.x); o.y = (short)f2bf(v.y);
  o.z = (short)f2bf(v.z); o.w = (short)f2bf(v.w);
  reinterpret_cast<short4v*>(out)[i] = o;
}

// ---------------- transpose + cast: in KxN fp32 -> out NxK bf16 ----------------
__global__ __launch_bounds__(256) void transp_cast(const float* __restrict__ in,
                                                   short* __restrict__ out,
                                                   int K, int N) {
  __shared__ float t[32][33];
  int bn = blockIdx.x * 32, bk = blockIdx.y * 32;
  int tx = threadIdx.x, ty = threadIdx.y;
  for (int i = ty; i < 32; i += 8)
    t[i][tx] = in[(size_t)(bk + i) * N + bn + tx];
  __syncthreads();
  for (int i = ty; i < 32; i += 8)
    out[(size_t)(bn + i) * K + bk + tx] = (short)f2bf(t[tx][i]);
}

// ---------------- fused Wq/Wk/Wv transpose+cast into Wqkv (NxK, N=3072) -----
__global__ __launch_bounds__(256) void transp_qkv(const float* __restrict__ Wq,
                                                  const float* __restrict__ Wk,
                                                  const float* __restrict__ Wv,
                                                  short* __restrict__ out) {
  __shared__ float t[32][33];
  const int K = 2048;
  int bnG = blockIdx.x * 32;
  int bk = blockIdx.y * 32;
  const float* src; int N, bn;
  if (bnG < 2048)      { src = Wq; N = 2048; bn = bnG; }
  else if (bnG < 2560) { src = Wk; N = 512;  bn = bnG - 2048; }
  else                 { src = Wv; N = 512;  bn = bnG - 2560; }
  int tx = threadIdx.x, ty = threadIdx.y;
  for (int i = ty; i < 32; i += 8)
    t[i][tx] = src[(size_t)(bk + i) * N + bn + tx];
  __syncthreads();
  for (int i = ty; i < 32; i += 8)
    out[(size_t)(bnG + i) * K + bk + tx] = (short)f2bf(t[tx][i]);
}

// ---------------- bf16 transpose: per head [2048 pos][128 dh] -> [128 dh][2048 pos]
__global__ __launch_bounds__(256) void transp_v(const short* __restrict__ V,
                                                short* __restrict__ VTo) {
  __shared__ short t[32][34];
  const int hd = blockIdx.z;
  const int p0 = blockIdx.x * 32, d0 = blockIdx.y * 32;
  const short* src = V + (size_t)hd * 2048 * 128;
  short* dst = VTo + (size_t)hd * 2048 * 128;
  int tx = threadIdx.x, ty = threadIdx.y;
  for (int i = ty; i < 32; i += 8)
    t[i][tx] = src[(size_t)(p0 + i) * 128 + d0 + tx];
  __syncthreads();
  for (int i = ty; i < 32; i += 8)
    dst[(size_t)(d0 + i) * 2048 + p0 + tx] = t[tx][i];
}

// ---------------- QKV GEMM: 256x256x(BK=64), 8-phase, counted vmcnt ---------
// A (4096x2048 bf16), Bt (3072x2048 bf16) -> fused RoPE -> Q/K/V head-major.
// 8 waves, interleaved 2Mx4N: wave (wr,wc) m-frag rows (wr+2m)*16, n-frag
// cols (wc+4n)*16 -> phase quadrant (mh,nh) touches only A-half mh / B-half
// nh, so halves die early and staging overwrites them mid-tile. 8 phases per
// 2 K-tiles, one half-tile (2 loads) staged per phase, vmcnt(8) per phase
// (4 half-tiles in flight, never drained to 0 in the loop).
__global__ __launch_bounds__(512, 2) void qkv8p(
    const short* __restrict__ A, const short* __restrict__ Bt,
    short* __restrict__ Qo, short* __restrict__ Ko, short* __restrict__ Vo,
    const float* __restrict__ cosT, const float* __restrict__ sinT) {
  __shared__ __align__(16) short As[2][2][8192];   // [dbuf][Mhalf][128*64]
  __shared__ __align__(16) short Bs[2][2][8192];   // [dbuf][Nhalf][128*64]
  const int tid = threadIdx.x;
  const int l = tid & 63, l15 = l & 15, l4 = l >> 4;
  const int wid = tid >> 6, wr = wid >> 2, wc = wid & 3;
  const int sid = (blockIdx.x & 7) * 24 + (blockIdx.x >> 3);  // XCD swizzle (192%8==0)
  const int bm = sid & 15, bn = sid >> 4;                     // 16 x 12
  const int swz = (l15 & 7) << 4;

  const int c0r = tid >> 3, c0s = (tid & 7) ^ (c0r & 7);
  const int c1r = (tid + 512) >> 3, c1s = (tid & 7) ^ (c1r & 7);

  auto SA = [&](int t, int h) {
    if (t >= 32) return;
    short* dst = As[t & 1][h];
    lds_cp16(A + (size_t)(bm * 256 + h * 128 + c0r) * 2048 + t * 64 + c0s * 8,
             (char*)dst + tid * 16);
    lds_cp16(A + (size_t)(bm * 256 + h * 128 + c1r) * 2048 + t * 64 + c1s * 8,
             (char*)dst + tid * 16 + 8192);
  };
  auto SB = [&](int t, int h) {
    if (t >= 32) return;
    short* dst = Bs[t & 1][h];
    lds_cp16(Bt + (size_t)(bn * 256 + h * 128 + c0r) * 2048 + t * 64 + c0s * 8,
             (char*)dst + tid * 16);
    lds_cp16(Bt + (size_t)(bn * 256 + h * 128 + c1r) * 2048 + t * 64 + c1s * 8,
             (char*)dst + tid * 16 + 8192);
  };
  auto rdA = [&](int d, int mh, int ml, int ks) {
    const int lr = wr * 16 + ml * 32 + l15;
    return *(const bf16x8*)((const char*)As[d][mh] + lr * 128 + ((ks * 64 + l4 * 16) ^ swz));
  };
  auto rdB = [&](int d, int nh, int nl, int ks) {
    const int lc = wc * 16 + nl * 64 + l15;
    return *(const bf16x8*)((const char*)Bs[d][nh] + lc * 128 + ((ks * 64 + l4 * 16) ^ swz));
  };

  f32x4 acc[8][4];
#pragma unroll
  for (int m = 0; m < 8; m++)
#pragma unroll
    for (int n = 0; n < 4; n++) acc[m][n] = (f32x4){0.f, 0.f, 0.f, 0.f};

  // prologue: tile0 complete + tile1 (A-h0, B-h0); ledger order matters
  SA(0, 0); SB(0, 0); SB(0, 1); SA(0, 1); SA(1, 0); SB(1, 0);
  asm volatile("s_waitcnt vmcnt(8)" ::: "memory");   // A0h0,B0h0 complete
  GBAR();

  for (int I = 0; I < 16; I++) {
    const int T = 2 * I;
    auto phase = [&](int d, int mh, int nh, auto stage) {
      bf16x8 a[4][2], b[2][2];
#pragma unroll
      for (int ml = 0; ml < 4; ml++)
#pragma unroll
        for (int ks = 0; ks < 2; ks++) a[ml][ks] = rdA(d, mh, ml, ks);
#pragma unroll
      for (int nl = 0; nl < 2; nl++)
#pragma unroll
        for (int ks = 0; ks < 2; ks++) b[nl][ks] = rdB(d, nh, nl, ks);
      stage();
      asm volatile("s_waitcnt vmcnt(8)" ::: "memory");
      GBAR();
      asm volatile("s_waitcnt lgkmcnt(0)" ::: "memory");
      __builtin_amdgcn_sched_barrier(0);
      __builtin_amdgcn_s_setprio(1);
#pragma unroll
      for (int ml = 0; ml < 4; ml++)
#pragma unroll
        for (int nl = 0; nl < 2; nl++)
#pragma unroll
          for (int ks = 0; ks < 2; ks++)
            acc[mh * 4 + ml][nh * 2 + nl] = __builtin_amdgcn_mfma_f32_16x16x32_bf16(
                a[ml][ks], b[nl][ks], acc[mh * 4 + ml][nh * 2 + nl], 0, 0, 0);
      __builtin_amdgcn_s_setprio(0);
      GBAR();
    };
    // tile T (buf0): quadrants; staging per verified ledger
    phase(0, 0, 0, [&] { SB(T + 1, 1); });
    phase(0, 0, 1, [&] { SA(T + 1, 1); });
    phase(0, 1, 0, [&] { SA(T + 2, 0); });
    phase(0, 1, 1, [&] { SB(T + 2, 0); });
    // tile T+1 (buf1)
    phase(1, 0, 0, [&] { SB(T + 2, 1); });
    phase(1, 0, 1, [&] { SA(T + 2, 1); });
    phase(1, 1, 0, [&] { SA(T + 3, 0); });
    phase(1, 1, 1, [&] { SB(T + 3, 0); });
  }

  // RoPE epilogue: col = bn*256 + wc*16 + n*64 + l15 -> head = bn*2 + (n>>1),
  // dh = wc*16 + l15 (+64 for odd n). Rows: bm*256 + (wr+2m)*16 + l4*4 + ri.
#pragma unroll
  for (int m = 0; m < 8; m++) {
#pragma unroll
    for (int ri = 0; ri < 4; ri++) {
      const int grow = bm * 256 + (wr + 2 * m) * 16 + l4 * 4 + ri;
      const int bb = grow >> 11, pos = grow & 2047;
      const int dh = wc * 16 + l15;
      const float cv = cosT[pos * 128 + dh];
      const float sv = sinT[pos * 128 + dh];
#pragma unroll
      for (int hp = 0; hp < 2; hp++) {
        const int head = bn * 2 + hp;
        const float xlo = acc[m][2 * hp][ri], xhi = acc[m][2 * hp + 1][ri];
        short* dst;
        if (head < 16)      dst = Qo + ((size_t)(bb * 16 + head) * 2048 + pos) * 128;
        else if (head < 20) dst = Ko + ((size_t)(bb * 4 + head - 16) * 2048 + pos) * 128;
        else                dst = Vo + ((size_t)(bb * 4 + head - 20) * 2048 + pos) * 128;
        if (head < 20) {
          dst[dh]      = (short)f2bf(xlo * cv - xhi * sv);
          dst[dh + 64] = (short)f2bf(xhi * cv + xlo * sv);
        } else {
          dst[dh]      = (short)f2bf(xlo);
          dst[dh + 64] = (short)f2bf(xhi);
        }
      }
    }
  }
}

// ---------------- out-proj GEMM (round-6 gemm8p, BM=128, EPI=0) -------------
template <int BM>
__global__ __launch_bounds__(512, 2) void gemm8p(
    const short* __restrict__ A, const short* __restrict__ Bt,
    float* __restrict__ C, int N, int Kd, int nbm) {
  constexpr int NM = BM / 64;
  __shared__ __align__(16) short As[2][BM * 64];
  __shared__ __align__(16) short Bs[2][256 * 64];
  const int tid = threadIdx.x;
  const int l = tid & 63, l15 = l & 15, l4 = l >> 4;
  const int wid = tid >> 6, wr = wid >> 1, wc = wid & 1;
  const int cpx = gridDim.x >> 3;
  const int sid = (blockIdx.x & 7) * cpx + (blockIdx.x >> 3);
  const int bm = sid % nbm, bn = sid / nbm;

  const int srow = tid >> 3;
  const int sch = tid & 7;

  auto stA = [&](int dbuf, int k0, int i) {
    const int rl = srow + i * 64;
    const int c = sch ^ (rl & 7);
    lds_cp16(A + (size_t)(bm * BM + rl) * Kd + k0 + c * 8,
             (char*)As[dbuf] + tid * 16 + i * 8192);
  };
  auto stB = [&](int dbuf, int k0, int j) {
    const int rl = srow + j * 64;
    const int c = sch ^ (rl & 7);
    lds_cp16(Bt + (size_t)(bn * 256 + rl) * Kd + k0 + c * 8,
             (char*)Bs[dbuf] + tid * 16 + j * 8192);
  };
  auto rdA = [&](int dbuf, int m, int kb) {
    const int row = wr * (BM / 4) + m * 16 + l15;
    return *(const bf16x8*)((const char*)As[dbuf] + (row << 7) +
                            ((kb * 64 + l4 * 16) ^ ((row & 7) << 4)));
  };
  auto rdB = [&](int dbuf, int nh, int f, int kb) {
    const int row = wc * 128 + nh * 64 + f * 16 + l15;
    return *(const bf16x8*)((const char*)Bs[dbuf] + (row << 7) +
                            ((kb * 64 + l4 * 16) ^ ((row & 7) << 4)));
  };

  f32x4 acc[NM][8];
#pragma unroll
  for (int m = 0; m < NM; m++)
#pragma unroll
    for (int n = 0; n < 8; n++) acc[m][n] = (f32x4){0.f, 0.f, 0.f, 0.f};

  const int NT = Kd >> 6;

#pragma unroll
  for (int i = 0; i < NM; i++) stA(0, 0, i);
#pragma unroll
  for (int j = 0; j < 4; j++) stB(0, 0, j);
  asm volatile("s_waitcnt vmcnt(0)" ::: "memory");
  GBAR();

  for (int kt = 0; kt < NT; kt++) {
    const int buf = kt & 1, nbf = buf ^ 1;
    const bool stg = (kt + 1 < NT);
    const int k1 = (kt + 1) << 6;
    bf16x8 a[NM], b[4];

#pragma unroll
    for (int m = 0; m < NM; m++) a[m] = rdA(buf, m, 0);
#pragma unroll
    for (int f = 0; f < 4; f++) b[f] = rdB(buf, 0, f, 0);
    if (stg) { stA(nbf, k1, 0); stA(nbf, k1, 1); }
    if (stg) asm volatile("s_waitcnt vmcnt(2)" ::: "memory");
    else     asm volatile("s_waitcnt vmcnt(0)" ::: "memory");
    GBAR();
    asm volatile("s_waitcnt lgkmcnt(0)" ::: "memory");
    __builtin_amdgcn_sched_barrier(0);
    __builtin_amdgcn_s_setprio(1);
#pragma unroll
    for (int m = 0; m < NM; m++)
#pragma unroll
      for (int f = 0; f < 4; f++)
        acc[m][f] = __builtin_amdgcn_mfma_f32_16x16x32_bf16(a[m], b[f], acc[m][f], 0, 0, 0);
    __builtin_amdgcn_s_setprio(0);
    GBAR();

#pragma unroll
    for (int f = 0; f < 4; f++) b[f] = rdB(buf, 1, f, 0);
    if (stg) { stB(nbf, k1, 0); stB(nbf, k1, 2); }
    GBAR();
    asm volatile("s_waitcnt lgkmcnt(0)" ::: "memory");
    __builtin_amdgcn_sched_barrier(0);
    __builtin_amdgcn_s_setprio(1);
#pragma unroll
    for (int m = 0; m < NM; m++)
#pragma unroll
      for (int f = 0; f < 4; f++)
        acc[m][4 + f] = __builtin_amdgcn_mfma_f32_16x16x32_bf16(a[m], b[f], acc[m][4 + f], 0, 0, 0);
    __builtin_amdgcn_s_setprio(0);
    GBAR();

#pragma unroll
    for (int m = 0; m < NM; m++) a[m] = rdA(buf, m, 1);
#pragma unroll
    for (int f = 0; f < 4; f++) b[f] = rdB(buf, 0, f, 1);
    if (stg) { stB(nbf, k1, 1); stB(nbf, k1, 3); }
    GBAR();
    asm volatile("s_waitcnt lgkmcnt(0)" ::: "memory");
    __builtin_amdgcn_sched_barrier(0);
    __builtin_amdgcn_s_setprio(1);
#pragma unroll
    for (int m = 0; m < NM; m++)
#pragma unroll
      for (int f = 0; f < 4; f++)
        acc[m][f] = __builtin_amdgcn_mfma_f32_16x16x32_bf16(a[m], b[f], acc[m][f], 0, 0, 0);
    __builtin_amdgcn_s_setprio(0);
    GBAR();

#pragma unroll
    for (int f = 0; f < 4; f++) b[f] = rdB(buf, 1, f, 1);
    if (stg) asm volatile("s_waitcnt vmcnt(2)" ::: "memory");
    GBAR();
    asm volatile("s_waitcnt lgkmcnt(0)" ::: "memory");
    __builtin_amdgcn_sched_barrier(0);
    __builtin_amdgcn_s_setprio(1);
#pragma unroll
    for (int m = 0; m < NM; m++)
#pragma unroll
      for (int f = 0; f < 4; f++)
        acc[m][4 + f] = __builtin_amdgcn_mfma_f32_16x16x32_bf16(a[m], b[f], acc[m][4 + f], 0, 0, 0);
    __builtin_amdgcn_s_setprio(0);
    GBAR();
  }

#pragma unroll
  for (int m = 0; m < NM; m++) {
    const int grow = bm * BM + wr * (BM / 4) + m * 16 + l4 * 4;
#pragma unroll
    for (int ni = 0; ni < 8; ni++) {
      const int col = bn * 256 + wc * 128 + (ni >> 2) * 64 + (ni & 3) * 16 + l15;
#pragma unroll
      for (int r = 0; r < 4; r++)
        C[(size_t)(grow + r) * N + col] = acc[m][ni][r];
    }
  }
}

// ---------------- flash attention, causal, GQA (round-10 verified) ----------
__global__ __launch_bounds__(256) void attn_fwd(
    const short* __restrict__ Q, const short* __restrict__ K,
    const short* __restrict__ VT, short* __restrict__ AO) {
  __shared__ __align__(16) short Ks[2][64 * 128];
  __shared__ __align__(16) short VTs[2][128 * 64];
  __shared__ __align__(16) short Pl[4][16 * 64];
  const int tid = threadIdx.x;
  const int w = tid >> 6, l = tid & 63;
  const int l15 = l & 15, l4 = l >> 4;
  const int bid = blockIdx.x;
  const int lg = (bid & 7) * 64 + (bid >> 3);
  const int bh = lg >> 4, pp = lg & 15;
  const int b = bh >> 4, h = bh & 15, kv = h >> 2;
  const short* Qbase = Q + (size_t)(b * 16 + h) * 2048 * 128;
  const short* Kbase = K + (size_t)(b * 4 + kv) * 2048 * 128;
  const short* VTb   = VT + (size_t)(b * 4 + kv) * 2048 * 128;

  int rk[4], ck[4], dv[4], kc[4];
#pragma unroll
  for (int i = 0; i < 4; i++) {
    const int c = tid + i * 256;
    rk[i] = c >> 4; ck[i] = (c & 15) ^ (rk[i] & 7);
    dv[i] = c >> 3; kc[i] = (c & 7) ^ (dv[i] & 7);
  }

  const float SCL = 0.08838834764831845f * 1.4426950408889634f;

  bf16x8 ones;
#pragma unroll
  for (int j = 0; j < 8; j++) ones[j] = (short)0x3F80;

  for (int qq = 0; qq < 2; qq++) {
    const int qt = qq ? (31 - pp) : pp;
    const int q0w = qt * 64 + w * 16;

    bf16x8 qf[4];
#pragma unroll
    for (int kb = 0; kb < 4; kb++)
      qf[kb] = *(const bf16x8*)(Qbase + (size_t)(q0w + l15) * 128 + kb * 32 + l4 * 8);

    f32x4 oacc[8];
#pragma unroll
    for (int i = 0; i < 8; i++) oacc[i] = (f32x4){0.f, 0.f, 0.f, 0.f};
    f32x4 lacc = (f32x4){0.f, 0.f, 0.f, 0.f};

    const int ntiles = qt + 1;

    __syncthreads();
#pragma unroll
    for (int i = 0; i < 4; i++) {
      lds_cp16(Kbase + rk[i] * 128 + ck[i] * 8, (char*)Ks[0] + i * 4096 + tid * 16);
      lds_cp16(VTb + (size_t)dv[i] * 2048 + kc[i] * 8, (char*)VTs[0] + i * 4096 + tid * 16);
    }

    for (int nt = 0; nt < ntiles; nt++) {
      const int k0 = nt * 64, buf = nt & 1;
      __syncthreads();
      if (nt + 1 < ntiles) {
        const int kn = k0 + 64, bnx = buf ^ 1;
#pragma unroll
        for (int i = 0; i < 4; i++) {
          lds_cp16(Kbase + (size_t)(kn + rk[i]) * 128 + ck[i] * 8,
                   (char*)Ks[bnx] + i * 4096 + tid * 16);
          lds_cp16(VTb + (size_t)dv[i] * 2048 + kn + kc[i] * 8,
                   (char*)VTs[bnx] + i * 4096 + tid * 16);
        }
      }

      f32x4 sa[4];
#pragma unroll
      for (int kg = 0; kg < 4; kg++) sa[kg] = (f32x4){0.f, 0.f, 0.f, 0.f};
      __builtin_amdgcn_s_setprio(1);
#pragma unroll
      for (int kg = 0; kg < 4; kg++) {
        const int row = kg * 16 + l15;
        const int swz = (row & 7) << 4;
#pragma unroll
        for (int kb = 0; kb < 4; kb++) {
          const char* kp = (const char*)Ks[buf] + row * 256 + ((kb * 64 + l4 * 16) ^ swz);
          sa[kg] = __builtin_amdgcn_mfma_f32_16x16x32_bf16(qf[kb], *(const bf16x8*)kp, sa[kg], 0, 0, 0);
        }
      }
      __builtin_amdgcn_s_setprio(0);

      float p[4][4];
      const bool domask = (k0 + 63 > q0w);
#pragma unroll
      for (int kg = 0; kg < 4; kg++)
#pragma unroll
        for (int r = 0; r < 4; r++) {
          float pv = exp2f(sa[kg][r] * SCL);
          if (domask) {
            int qrow = q0w + l4 * 4 + r;
            if (k0 + kg * 16 + l15 > qrow) pv = 0.f;
          }
          p[kg][r] = pv;
        }

#pragma unroll
      for (int r = 0; r < 4; r++) {
        const int rw = l4 * 4 + r;
        const int swz = (rw & 7) << 4;
#pragma unroll
        for (int kg = 0; kg < 4; kg++)
          *(short*)((char*)Pl[w] + (rw * 128 + ((kg * 32 + l15 * 2) ^ swz))) =
              f2bf_hw(p[kg][r]);
      }
      asm volatile("s_waitcnt lgkmcnt(0)" ::: "memory");
      bf16x8 pf[2];
#pragma unroll
      for (int ks = 0; ks < 2; ks++)
        pf[ks] = *(const bf16x8*)((const char*)Pl[w] +
                 (l15 * 128 + ((ks * 64 + l4 * 16) ^ ((l15 & 7) << 4))));

      __builtin_amdgcn_s_setprio(1);
#pragma unroll
      for (int nb = 0; nb < 8; nb++) {
        const int d = nb * 16 + l15;
        const int dsw = (d & 7) << 4;
#pragma unroll
        for (int ks = 0; ks < 2; ks++) {
          const char* vp = (const char*)VTs[buf] + d * 128 + ((ks * 64 + l4 * 16) ^ dsw);
          oacc[nb] = __builtin_amdgcn_mfma_f32_16x16x32_bf16(pf[ks], *(const bf16x8*)vp, oacc[nb], 0, 0, 0);
        }
      }
      lacc = __builtin_amdgcn_mfma_f32_16x16x32_bf16(pf[0], ones, lacc, 0, 0, 0);
      lacc = __builtin_amdgcn_mfma_f32_16x16x32_bf16(pf[1], ones, lacc, 0, 0, 0);
      __builtin_amdgcn_s_setprio(0);
    }

#pragma unroll
    for (int r = 0; r < 4; r++) {
      float inv = 1.0f / lacc[r];
      size_t rowb = ((size_t)b * 2048 + q0w + l4 * 4 + r) * 2048 + h * 128;
#pragma unroll
      for (int nb = 0; nb < 8; nb++)
        AO[rowb + nb * 16 + l15] = f2bf_hw(oacc[nb][r] * inv);
    }
  }
}

extern "C" void kernel_launch(void* const* d_in, const int* in_sizes, int n_in,
                              void* d_out, int out_size, void* d_ws, size_t ws_size,
                              hipStream_t stream) {
  const float* hs   = (const float*)d_in[0];
  const float* cosT = (const float*)d_in[1];
  const float* sinT = (const float*)d_in[2];
  const float* Wq   = (const float*)d_in[3];
  const float* Wk   = (const float*)d_in[4];
  const float* Wv   = (const float*)d_in[5];
  const float* Wo   = (const float*)d_in[6];
  float* out = (float*)d_out;

  char* p = (char*)d_ws;
  short* Xb   = (short*)p; p += (size_t)4096 * 2048 * 2;   // reused as AO
  short* Wqkv = (short*)p; p += (size_t)3072 * 2048 * 2;
  short* Wot  = (short*)p; p += (size_t)2048 * 2048 * 2;
  short* Qb   = (short*)p; p += (size_t)2 * 16 * 2048 * 128 * 2;
  short* Kb   = (short*)p; p += (size_t)2 * 4 * 2048 * 128 * 2;
  short* Vb   = (short*)p; p += (size_t)2 * 4 * 2048 * 128 * 2;
  short* VTb  = (short*)p; p += (size_t)2 * 4 * 2048 * 128 * 2;
  short* AO   = Xb;

  cast_x<<<8192, 256, 0, stream>>>(hs, Xb, 2097152);
  transp_qkv<<<dim3(96, 64), dim3(32, 8), 0, stream>>>(Wq, Wk, Wv, Wqkv);
  transp_cast<<<dim3(64, 64), dim3(32, 8), 0, stream>>>(Wo, Wot, 2048, 2048);

  // QKV: M=4096, N=3072 -> 192 blocks, 8-phase schedule, fused RoPE epilogue
  qkv8p<<<192, 512, 0, stream>>>(Xb, Wqkv, Qb, Kb, Vb, cosT, sinT);
  transp_v<<<dim3(64, 4, 8), dim3(32, 8), 0, stream>>>(Vb, VTb);
  attn_fwd<<<512, 256, 0, stream>>>(Qb, Kb, VTb, AO);
  // out-proj: M=4096, N=2048 -> 256 blocks
  gemm8p<128><<<256, 512, 0, stream>>>(AO, Wot, out, 2048, 2048, 32);
}

// Round 13
// 215.478 us; speedup vs baseline: 1.2078x; 1.1034x over previous
//
#include <hip/hip_runtime.h>
#include <hip/hip_bf16.h>

typedef __attribute__((ext_vector_type(8))) short bf16x8;
typedef __attribute__((ext_vector_type(4))) float f32x4;
typedef __attribute__((ext_vector_type(4))) short short4v;

__device__ __forceinline__ unsigned short f2bf(float f) {
  union { float f; unsigned u; } x; x.f = f;
  return (unsigned short)((x.u + 0x7FFFu + ((x.u >> 16) & 1u)) >> 16);
}

__device__ __forceinline__ short f2bf_hw(float f) {
  __hip_bfloat16 h = __float2bfloat16(f);
  return *(short*)&h;
}

__device__ __forceinline__ void lds_cp16(const void* g, void* l) {
  __builtin_amdgcn_global_load_lds(
      (const __attribute__((address_space(1))) void*)g,
      (__attribute__((address_space(3))) void*)l,
      16, 0, 0);
}

#define GBAR() do { __builtin_amdgcn_s_barrier(); __builtin_amdgcn_sched_barrier(0); } while (0)

// ---------------- cast fp32 -> bf16, vectorized ----------------
__global__ __launch_bounds__(256) void cast_x(const float* __restrict__ in,
                                              short* __restrict__ out, int n4) {
  int i = blockIdx.x * 256 + threadIdx.x;
  if (i >= n4) return;
  float4 v = reinterpret_cast<const float4*>(in)[i];
  short4v o;
  o.x = (short)f2bf(v.x); o.y = (short)f2bf(v.y);
  o.z = (short)f2bf(v.z); o.w = (short)f2bf(v.w);
  reinterpret_cast<short4v*>(out)[i] = o;
}

// ---------------- fused weight transpose+cast: Wq/Wk/Wv -> Wqkv, Wo -> Wot ---
// bnG in [0,5120): [0,2048) Wq, [2048,2560) Wk, [2560,3072) Wv -> Wqkv rows;
// [3072,5120) Wo -> Wot rows. All K=2048.
__global__ __launch_bounds__(256) void transp_w(const float* __restrict__ Wq,
                                                const float* __restrict__ Wk,
                                                const float* __restrict__ Wv,
                                                const float* __restrict__ Wo,
                                                short* __restrict__ Wqkv,
                                                short* __restrict__ Wot) {
  __shared__ float t[32][33];
  const int K = 2048;
  int bnG = blockIdx.x * 32;
  int bk = blockIdx.y * 32;
  const float* src; int N, bn; short* out; int orow;
  if (bnG < 2048)      { src = Wq; N = 2048; bn = bnG;        out = Wqkv; orow = bnG; }
  else if (bnG < 2560) { src = Wk; N = 512;  bn = bnG - 2048; out = Wqkv; orow = bnG; }
  else if (bnG < 3072) { src = Wv; N = 512;  bn = bnG - 2560; out = Wqkv; orow = bnG; }
  else                 { src = Wo; N = 2048; bn = bnG - 3072; out = Wot;  orow = bnG - 3072; }
  int tx = threadIdx.x, ty = threadIdx.y;
  for (int i = ty; i < 32; i += 8)
    t[i][tx] = src[(size_t)(bk + i) * N + bn + tx];
  __syncthreads();
  for (int i = ty; i < 32; i += 8)
    out[(size_t)(orow + i) * K + bk + tx] = (short)f2bf(t[tx][i]);
}

// ---------------- bf16 transpose: per head [2048 pos][128 dh] -> [128 dh][2048 pos]
__global__ __launch_bounds__(256) void transp_v(const short* __restrict__ V,
                                                short* __restrict__ VTo) {
  __shared__ short t[32][34];
  const int hd = blockIdx.z;
  const int p0 = blockIdx.x * 32, d0 = blockIdx.y * 32;
  const short* src = V + (size_t)hd * 2048 * 128;
  short* dst = VTo + (size_t)hd * 2048 * 128;
  int tx = threadIdx.x, ty = threadIdx.y;
  for (int i = ty; i < 32; i += 8)
    t[i][tx] = src[(size_t)(p0 + i) * 128 + d0 + tx];
  __syncthreads();
  for (int i = ty; i < 32; i += 8)
    dst[(size_t)(d0 + i) * 2048 + p0 + tx] = t[tx][i];
}

// ---------------- 8-wave deep-phase GEMM (round-6/10 verified) ---------------
template <int BM, int EPI>
__global__ __launch_bounds__(512, 2) void gemm8p(
    const short* __restrict__ A, const short* __restrict__ Bt,
    float* __restrict__ C,
    short* __restrict__ Qo, short* __restrict__ Ko, short* __restrict__ Vo,
    const float* __restrict__ cosT, const float* __restrict__ sinT,
    int N, int Kd, int nbm) {
  constexpr int NM = BM / 64;
  __shared__ __align__(16) short As[2][BM * 64];
  __shared__ __align__(16) short Bs[2][256 * 64];
  const int tid = threadIdx.x;
  const int l = tid & 63, l15 = l & 15, l4 = l >> 4;
  const int wid = tid >> 6, wr = wid >> 1, wc = wid & 1;
  const int cpx = gridDim.x >> 3;
  const int sid = (blockIdx.x & 7) * cpx + (blockIdx.x >> 3);
  const int bm = sid % nbm, bn = sid / nbm;

  const int srow = tid >> 3;
  const int sch = tid & 7;

  auto stA = [&](int dbuf, int k0, int i) {
    const int rl = srow + i * 64;
    const int c = sch ^ (rl & 7);
    lds_cp16(A + (size_t)(bm * BM + rl) * Kd + k0 + c * 8,
             (char*)As[dbuf] + tid * 16 + i * 8192);
  };
  auto stB = [&](int dbuf, int k0, int j) {
    const int rl = srow + j * 64;
    const int c = sch ^ (rl & 7);
    lds_cp16(Bt + (size_t)(bn * 256 + rl) * Kd + k0 + c * 8,
             (char*)Bs[dbuf] + tid * 16 + j * 8192);
  };
  auto rdA = [&](int dbuf, int m, int kb) {
    const int row = wr * (BM / 4) + m * 16 + l15;
    return *(const bf16x8*)((const char*)As[dbuf] + (row << 7) +
                            ((kb * 64 + l4 * 16) ^ ((row & 7) << 4)));
  };
  auto rdB = [&](int dbuf, int nh, int f, int kb) {
    const int row = wc * 128 + nh * 64 + f * 16 + l15;
    return *(const bf16x8*)((const char*)Bs[dbuf] + (row << 7) +
                            ((kb * 64 + l4 * 16) ^ ((row & 7) << 4)));
  };

  f32x4 acc[NM][8];
#pragma unroll
  for (int m = 0; m < NM; m++)
#pragma unroll
    for (int n = 0; n < 8; n++) acc[m][n] = (f32x4){0.f, 0.f, 0.f, 0.f};

  const int NT = Kd >> 6;

#pragma unroll
  for (int i = 0; i < NM; i++) stA(0, 0, i);
#pragma unroll
  for (int j = 0; j < 4; j++) stB(0, 0, j);
  asm volatile("s_waitcnt vmcnt(0)" ::: "memory");
  GBAR();

  for (int kt = 0; kt < NT; kt++) {
    const int buf = kt & 1, nbf = buf ^ 1;
    const bool stg = (kt + 1 < NT);
    const int k1 = (kt + 1) << 6;
    bf16x8 a[NM], b[4];

    // ---------- phase 0 ----------
#pragma unroll
    for (int m = 0; m < NM; m++) a[m] = rdA(buf, m, 0);
#pragma unroll
    for (int f = 0; f < 4; f++) b[f] = rdB(buf, 0, f, 0);
    if (stg) { stA(nbf, k1, 0); stA(nbf, k1, 1); }
    if (stg) asm volatile("s_waitcnt vmcnt(2)" ::: "memory");
    else     asm volatile("s_waitcnt vmcnt(0)" ::: "memory");
    GBAR();
    asm volatile("s_waitcnt lgkmcnt(0)" ::: "memory");
    __builtin_amdgcn_sched_barrier(0);
    __builtin_amdgcn_s_setprio(1);
#pragma unroll
    for (int m = 0; m < NM; m++)
#pragma unroll
      for (int f = 0; f < 4; f++)
        acc[m][f] = __builtin_amdgcn_mfma_f32_16x16x32_bf16(a[m], b[f], acc[m][f], 0, 0, 0);
    __builtin_amdgcn_s_setprio(0);
    GBAR();

    // ---------- phase 1 ----------
#pragma unroll
    for (int f = 0; f < 4; f++) b[f] = rdB(buf, 1, f, 0);
    if (stg) {
      if (BM == 256) { stA(nbf, k1, 2); stA(nbf, k1, 3); }
      else           { stB(nbf, k1, 0); stB(nbf, k1, 2); }
    }
    GBAR();
    asm volatile("s_waitcnt lgkmcnt(0)" ::: "memory");
    __builtin_amdgcn_sched_barrier(0);
    __builtin_amdgcn_s_setprio(1);
#pragma unroll
    for (int m = 0; m < NM; m++)
#pragma unroll
      for (int f = 0; f < 4; f++)
        acc[m][4 + f] = __builtin_amdgcn_mfma_f32_16x16x32_bf16(a[m], b[f], acc[m][4 + f], 0, 0, 0);
    __builtin_amdgcn_s_setprio(0);
    GBAR();

    // ---------- phase 2 ----------
#pragma unroll
    for (int m = 0; m < NM; m++) a[m] = rdA(buf, m, 1);
#pragma unroll
    for (int f = 0; f < 4; f++) b[f] = rdB(buf, 0, f, 1);
    if (stg) {
      if (BM == 256) { stB(nbf, k1, 0); stB(nbf, k1, 2); }
      else           { stB(nbf, k1, 1); stB(nbf, k1, 3); }
    }
    GBAR();
    asm volatile("s_waitcnt lgkmcnt(0)" ::: "memory");
    __builtin_amdgcn_sched_barrier(0);
    __builtin_amdgcn_s_setprio(1);
#pragma unroll
    for (int m = 0; m < NM; m++)
#pragma unroll
      for (int f = 0; f < 4; f++)
        acc[m][f] = __builtin_amdgcn_mfma_f32_16x16x32_bf16(a[m], b[f], acc[m][f], 0, 0, 0);
    __builtin_amdgcn_s_setprio(0);
    GBAR();

    // ---------- phase 3 ----------
#pragma unroll
    for (int f = 0; f < 4; f++) b[f] = rdB(buf, 1, f, 1);
    if (stg && BM == 256) { stB(nbf, k1, 1); stB(nbf, k1, 3); }
    if (stg) asm volatile("s_waitcnt vmcnt(2)" ::: "memory");
    GBAR();
    asm volatile("s_waitcnt lgkmcnt(0)" ::: "memory");
    __builtin_amdgcn_sched_barrier(0);
    __builtin_amdgcn_s_setprio(1);
#pragma unroll
    for (int m = 0; m < NM; m++)
#pragma unroll
      for (int f = 0; f < 4; f++)
        acc[m][4 + f] = __builtin_amdgcn_mfma_f32_16x16x32_bf16(a[m], b[f], acc[m][4 + f], 0, 0, 0);
    __builtin_amdgcn_s_setprio(0);
    GBAR();
  }

  if (EPI == 0) {
#pragma unroll
    for (int m = 0; m < NM; m++) {
      const int grow = bm * BM + wr * (BM / 4) + m * 16 + l4 * 4;
#pragma unroll
      for (int ni = 0; ni < 8; ni++) {
        const int col = bn * 256 + wc * 128 + (ni >> 2) * 64 + (ni & 3) * 16 + l15;
#pragma unroll
        for (int r = 0; r < 4; r++)
          C[(size_t)(grow + r) * N + col] = acc[m][ni][r];
      }
    }
  } else {
    const int head = bn * 2 + wc;
#pragma unroll
    for (int m = 0; m < NM; m++) {
#pragma unroll
      for (int r = 0; r < 4; r++) {
        const int grow = bm * BM + wr * (BM / 4) + m * 16 + l4 * 4 + r;
        const int bb = grow >> 11, pos = grow & 2047;
        if (head < 20) {
          float c4[4], s4[4];
#pragma unroll
          for (int ni = 0; ni < 4; ni++) {
            const int dh = ni * 16 + l15;
            c4[ni] = cosT[pos * 128 + dh];
            s4[ni] = sinT[pos * 128 + dh];
          }
          short* dst;
          if (head < 16) dst = Qo + ((size_t)(bb * 16 + head) * 2048 + pos) * 128;
          else           dst = Ko + ((size_t)(bb * 4 + (head - 16)) * 2048 + pos) * 128;
#pragma unroll
          for (int ni = 0; ni < 4; ni++) {
            const int dh = ni * 16 + l15;
            float xlo = acc[m][ni][r], xhi = acc[m][ni + 4][r];
            dst[dh]      = (short)f2bf(xlo * c4[ni] - xhi * s4[ni]);
            dst[dh + 64] = (short)f2bf(xhi * c4[ni] + xlo * s4[ni]);
          }
        } else {
          short* dst = Vo + ((size_t)(bb * 4 + (head - 20)) * 2048 + pos) * 128;
#pragma unroll
          for (int ni = 0; ni < 8; ni++)
            dst[(ni >> 2) * 64 + (ni & 3) * 16 + l15] = (short)f2bf(acc[m][ni][r]);
        }
      }
    }
  }
}

// ---------------- flash attention, causal, GQA (round-10 verified) ----------
__global__ __launch_bounds__(256) void attn_fwd(
    const short* __restrict__ Q, const short* __restrict__ K,
    const short* __restrict__ VT, short* __restrict__ AO) {
  __shared__ __align__(16) short Ks[2][64 * 128];
  __shared__ __align__(16) short VTs[2][128 * 64];
  __shared__ __align__(16) short Pl[4][16 * 64];
  const int tid = threadIdx.x;
  const int w = tid >> 6, l = tid & 63;
  const int l15 = l & 15, l4 = l >> 4;
  const int bid = blockIdx.x;
  const int lg = (bid & 7) * 64 + (bid >> 3);
  const int bh = lg >> 4, pp = lg & 15;
  const int b = bh >> 4, h = bh & 15, kv = h >> 2;
  const short* Qbase = Q + (size_t)(b * 16 + h) * 2048 * 128;
  const short* Kbase = K + (size_t)(b * 4 + kv) * 2048 * 128;
  const short* VTb   = VT + (size_t)(b * 4 + kv) * 2048 * 128;

  int rk[4], ck[4], dv[4], kc[4];
#pragma unroll
  for (int i = 0; i < 4; i++) {
    const int c = tid + i * 256;
    rk[i] = c >> 4; ck[i] = (c & 15) ^ (rk[i] & 7);
    dv[i] = c >> 3; kc[i] = (c & 7) ^ (dv[i] & 7);
  }

  const float SCL = 0.08838834764831845f * 1.4426950408889634f;

  bf16x8 ones;
#pragma unroll
  for (int j = 0; j < 8; j++) ones[j] = (short)0x3F80;

  for (int qq = 0; qq < 2; qq++) {
    const int qt = qq ? (31 - pp) : pp;
    const int q0w = qt * 64 + w * 16;

    bf16x8 qf[4];
#pragma unroll
    for (int kb = 0; kb < 4; kb++)
      qf[kb] = *(const bf16x8*)(Qbase + (size_t)(q0w + l15) * 128 + kb * 32 + l4 * 8);

    f32x4 oacc[8];
#pragma unroll
    for (int i = 0; i < 8; i++) oacc[i] = (f32x4){0.f, 0.f, 0.f, 0.f};
    f32x4 lacc = (f32x4){0.f, 0.f, 0.f, 0.f};

    const int ntiles = qt + 1;

    __syncthreads();
#pragma unroll
    for (int i = 0; i < 4; i++) {
      lds_cp16(Kbase + rk[i] * 128 + ck[i] * 8, (char*)Ks[0] + i * 4096 + tid * 16);
      lds_cp16(VTb + (size_t)dv[i] * 2048 + kc[i] * 8, (char*)VTs[0] + i * 4096 + tid * 16);
    }

    for (int nt = 0; nt < ntiles; nt++) {
      const int k0 = nt * 64, buf = nt & 1;
      __syncthreads();
      if (nt + 1 < ntiles) {
        const int kn = k0 + 64, bnx = buf ^ 1;
#pragma unroll
        for (int i = 0; i < 4; i++) {
          lds_cp16(Kbase + (size_t)(kn + rk[i]) * 128 + ck[i] * 8,
                   (char*)Ks[bnx] + i * 4096 + tid * 16);
          lds_cp16(VTb + (size_t)dv[i] * 2048 + kn + kc[i] * 8,
                   (char*)VTs[bnx] + i * 4096 + tid * 16);
        }
      }

      f32x4 sa[4];
#pragma unroll
      for (int kg = 0; kg < 4; kg++) sa[kg] = (f32x4){0.f, 0.f, 0.f, 0.f};
      __builtin_amdgcn_s_setprio(1);
#pragma unroll
      for (int kg = 0; kg < 4; kg++) {
        const int row = kg * 16 + l15;
        const int swz = (row & 7) << 4;
#pragma unroll
        for (int kb = 0; kb < 4; kb++) {
          const char* kp = (const char*)Ks[buf] + row * 256 + ((kb * 64 + l4 * 16) ^ swz);
          sa[kg] = __builtin_amdgcn_mfma_f32_16x16x32_bf16(qf[kb], *(const bf16x8*)kp, sa[kg], 0, 0, 0);
        }
      }
      __builtin_amdgcn_s_setprio(0);

      float p[4][4];
      const bool domask = (k0 + 63 > q0w);
#pragma unroll
      for (int kg = 0; kg < 4; kg++)
#pragma unroll
        for (int r = 0; r < 4; r++) {
          float pv = exp2f(sa[kg][r] * SCL);
          if (domask) {
            int qrow = q0w + l4 * 4 + r;
            if (k0 + kg * 16 + l15 > qrow) pv = 0.f;
          }
          p[kg][r] = pv;
        }

#pragma unroll
      for (int r = 0; r < 4; r++) {
        const int rw = l4 * 4 + r;
        const int swz = (rw & 7) << 4;
#pragma unroll
        for (int kg = 0; kg < 4; kg++)
          *(short*)((char*)Pl[w] + (rw * 128 + ((kg * 32 + l15 * 2) ^ swz))) =
              f2bf_hw(p[kg][r]);
      }
      asm volatile("s_waitcnt lgkmcnt(0)" ::: "memory");
      bf16x8 pf[2];
#pragma unroll
      for (int ks = 0; ks < 2; ks++)
        pf[ks] = *(const bf16x8*)((const char*)Pl[w] +
                 (l15 * 128 + ((ks * 64 + l4 * 16) ^ ((l15 & 7) << 4))));

      __builtin_amdgcn_s_setprio(1);
#pragma unroll
      for (int nb = 0; nb < 8; nb++) {
        const int d = nb * 16 + l15;
        const int dsw = (d & 7) << 4;
#pragma unroll
        for (int ks = 0; ks < 2; ks++) {
          const char* vp = (const char*)VTs[buf] + d * 128 + ((ks * 64 + l4 * 16) ^ dsw);
          oacc[nb] = __builtin_amdgcn_mfma_f32_16x16x32_bf16(pf[ks], *(const bf16x8*)vp, oacc[nb], 0, 0, 0);
        }
      }
      lacc = __builtin_amdgcn_mfma_f32_16x16x32_bf16(pf[0], ones, lacc, 0, 0, 0);
      lacc = __builtin_amdgcn_mfma_f32_16x16x32_bf16(pf[1], ones, lacc, 0, 0, 0);
      __builtin_amdgcn_s_setprio(0);
    }

#pragma unroll
    for (int r = 0; r < 4; r++) {
      float inv = 1.0f / lacc[r];
      size_t rowb = ((size_t)b * 2048 + q0w + l4 * 4 + r) * 2048 + h * 128;
#pragma unroll
      for (int nb = 0; nb < 8; nb++)
        AO[rowb + nb * 16 + l15] = f2bf_hw(oacc[nb][r] * inv);
    }
  }
}

extern "C" void kernel_launch(void* const* d_in, const int* in_sizes, int n_in,
                              void* d_out, int out_size, void* d_ws, size_t ws_size,
                              hipStream_t stream) {
  const float* hs   = (const float*)d_in[0];
  const float* cosT = (const float*)d_in[1];
  const float* sinT = (const float*)d_in[2];
  const float* Wq   = (const float*)d_in[3];
  const float* Wk   = (const float*)d_in[4];
  const float* Wv   = (const float*)d_in[5];
  const float* Wo   = (const float*)d_in[6];
  float* out = (float*)d_out;

  char* p = (char*)d_ws;
  short* Xb   = (short*)p; p += (size_t)4096 * 2048 * 2;   // reused as AO
  short* Wqkv = (short*)p; p += (size_t)3072 * 2048 * 2;
  short* Wot  = (short*)p; p += (size_t)2048 * 2048 * 2;
  short* Qb   = (short*)p; p += (size_t)2 * 16 * 2048 * 128 * 2;
  short* Kb   = (short*)p; p += (size_t)2 * 4 * 2048 * 128 * 2;
  short* Vb   = (short*)p; p += (size_t)2 * 4 * 2048 * 128 * 2;
  short* VTb  = (short*)p; p += (size_t)2 * 4 * 2048 * 128 * 2;
  short* AO   = Xb;

  cast_x<<<8192, 256, 0, stream>>>(hs, Xb, 2097152);
  transp_w<<<dim3(160, 64), dim3(32, 8), 0, stream>>>(Wq, Wk, Wv, Wo, Wqkv, Wot);

  // QKV: M=4096, N=3072 -> 192 blocks, fused RoPE epilogue
  gemm8p<256, 1><<<192, 512, 0, stream>>>(Xb, Wqkv, nullptr, Qb, Kb, Vb,
                                          cosT, sinT, 3072, 2048, 16);
  transp_v<<<dim3(64, 4, 8), dim3(32, 8), 0, stream>>>(Vb, VTb);
  attn_fwd<<<512, 256, 0, stream>>>(Qb, Kb, VTb, AO);
  // out-proj: M=4096, N=2048 -> 256 blocks
  gemm8p<128, 0><<<256, 512, 0, stream>>>(AO, Wot, out, nullptr, nullptr, nullptr,
                                          nullptr, nullptr, 2048, 2048, 32);
}

// Round 15
// 204.697 us; speedup vs baseline: 1.2714x; 1.0527x over previous
//
#include <hip/hip_runtime.h>
#include <hip/hip_bf16.h>

typedef __attribute__((ext_vector_type(8))) short bf16x8;
typedef __attribute__((ext_vector_type(4))) float f32x4;
typedef __attribute__((ext_vector_type(4))) short short4v;

__device__ __forceinline__ unsigned short f2bf(float f) {
  union { float f; unsigned u; } x; x.f = f;
  return (unsigned short)((x.u + 0x7FFFu + ((x.u >> 16) & 1u)) >> 16);
}

__device__ __forceinline__ short f2bf_hw(float f) {
  __hip_bfloat16 h = __float2bfloat16(f);
  return *(short*)&h;
}

__device__ __forceinline__ void lds_cp16(const void* g, void* l) {
  __builtin_amdgcn_global_load_lds(
      (const __attribute__((address_space(1))) void*)g,
      (__attribute__((address_space(3))) void*)l,
      16, 0, 0);
}

#define GBAR() do { __builtin_amdgcn_s_barrier(); __builtin_amdgcn_sched_barrier(0); } while (0)

// ---------------- cast fp32 -> bf16, vectorized ----------------
__global__ __launch_bounds__(256) void cast_x(const float* __restrict__ in,
                                              short* __restrict__ out, int n4) {
  int i = blockIdx.x * 256 + threadIdx.x;
  if (i >= n4) return;
  float4 v = reinterpret_cast<const float4*>(in)[i];
  short4v o;
  o.x = (short)f2bf(v.x); o.y = (short)f2bf(v.y);
  o.z = (short)f2bf(v.z); o.w = (short)f2bf(v.w);
  reinterpret_cast<short4v*>(out)[i] = o;
}

// ---------------- fused weight transpose+cast: Wq/Wk/Wv -> Wqkv, Wo -> Wot ---
__global__ __launch_bounds__(256) void transp_w(const float* __restrict__ Wq,
                                                const float* __restrict__ Wk,
                                                const float* __restrict__ Wv,
                                                const float* __restrict__ Wo,
                                                short* __restrict__ Wqkv,
                                                short* __restrict__ Wot) {
  __shared__ float t[32][33];
  const int K = 2048;
  int bnG = blockIdx.x * 32;
  int bk = blockIdx.y * 32;
  const float* src; int N, bn; short* out; int orow;
  if (bnG < 2048)      { src = Wq; N = 2048; bn = bnG;        out = Wqkv; orow = bnG; }
  else if (bnG < 2560) { src = Wk; N = 512;  bn = bnG - 2048; out = Wqkv; orow = bnG; }
  else if (bnG < 3072) { src = Wv; N = 512;  bn = bnG - 2560; out = Wqkv; orow = bnG; }
  else                 { src = Wo; N = 2048; bn = bnG - 3072; out = Wot;  orow = bnG - 3072; }
  int tx = threadIdx.x, ty = threadIdx.y;
  for (int i = ty; i < 32; i += 8)
    t[i][tx] = src[(size_t)(bk + i) * N + bn + tx];
  __syncthreads();
  for (int i = ty; i < 32; i += 8)
    out[(size_t)(orow + i) * K + bk + tx] = (short)f2bf(t[tx][i]);
}

// ---------------- bf16 transpose: per head [2048 pos][128 dh] -> [128 dh][2048 pos]
__global__ __launch_bounds__(256) void transp_v(const short* __restrict__ V,
                                                short* __restrict__ VTo) {
  __shared__ short t[32][34];
  const int hd = blockIdx.z;
  const int p0 = blockIdx.x * 32, d0 = blockIdx.y * 32;
  const short* src = V + (size_t)hd * 2048 * 128;
  short* dst = VTo + (size_t)hd * 2048 * 128;
  int tx = threadIdx.x, ty = threadIdx.y;
  for (int i = ty; i < 32; i += 8)
    t[i][tx] = src[(size_t)(p0 + i) * 128 + d0 + tx];
  __syncthreads();
  for (int i = ty; i < 32; i += 8)
    dst[(size_t)(d0 + i) * 2048 + p0 + tx] = t[tx][i];
}

// ---------------- QKV GEMM: 8-wave deep-phase, BM=256 BN=256 (r6/r10 verified)
template <int BM, int EPI>
__global__ __launch_bounds__(512, 2) void gemm8p(
    const short* __restrict__ A, const short* __restrict__ Bt,
    float* __restrict__ C,
    short* __restrict__ Qo, short* __restrict__ Ko, short* __restrict__ Vo,
    const float* __restrict__ cosT, const float* __restrict__ sinT,
    int N, int Kd, int nbm) {
  constexpr int NM = BM / 64;
  __shared__ __align__(16) short As[2][BM * 64];
  __shared__ __align__(16) short Bs[2][256 * 64];
  const int tid = threadIdx.x;
  const int l = tid & 63, l15 = l & 15, l4 = l >> 4;
  const int wid = tid >> 6, wr = wid >> 1, wc = wid & 1;
  const int cpx = gridDim.x >> 3;
  const int sid = (blockIdx.x & 7) * cpx + (blockIdx.x >> 3);
  const int bm = sid % nbm, bn = sid / nbm;

  const int srow = tid >> 3;
  const int sch = tid & 7;

  auto stA = [&](int dbuf, int k0, int i) {
    const int rl = srow + i * 64;
    const int c = sch ^ (rl & 7);
    lds_cp16(A + (size_t)(bm * BM + rl) * Kd + k0 + c * 8,
             (char*)As[dbuf] + tid * 16 + i * 8192);
  };
  auto stB = [&](int dbuf, int k0, int j) {
    const int rl = srow + j * 64;
    const int c = sch ^ (rl & 7);
    lds_cp16(Bt + (size_t)(bn * 256 + rl) * Kd + k0 + c * 8,
             (char*)Bs[dbuf] + tid * 16 + j * 8192);
  };
  auto rdA = [&](int dbuf, int m, int kb) {
    const int row = wr * (BM / 4) + m * 16 + l15;
    return *(const bf16x8*)((const char*)As[dbuf] + (row << 7) +
                            ((kb * 64 + l4 * 16) ^ ((row & 7) << 4)));
  };
  auto rdB = [&](int dbuf, int nh, int f, int kb) {
    const int row = wc * 128 + nh * 64 + f * 16 + l15;
    return *(const bf16x8*)((const char*)Bs[dbuf] + (row << 7) +
                            ((kb * 64 + l4 * 16) ^ ((row & 7) << 4)));
  };

  f32x4 acc[NM][8];
#pragma unroll
  for (int m = 0; m < NM; m++)
#pragma unroll
    for (int n = 0; n < 8; n++) acc[m][n] = (f32x4){0.f, 0.f, 0.f, 0.f};

  const int NT = Kd >> 6;

#pragma unroll
  for (int i = 0; i < NM; i++) stA(0, 0, i);
#pragma unroll
  for (int j = 0; j < 4; j++) stB(0, 0, j);
  asm volatile("s_waitcnt vmcnt(0)" ::: "memory");
  GBAR();

  for (int kt = 0; kt < NT; kt++) {
    const int buf = kt & 1, nbf = buf ^ 1;
    const bool stg = (kt + 1 < NT);
    const int k1 = (kt + 1) << 6;
    bf16x8 a[NM], b[4];

    // ---------- phase 0 ----------
#pragma unroll
    for (int m = 0; m < NM; m++) a[m] = rdA(buf, m, 0);
#pragma unroll
    for (int f = 0; f < 4; f++) b[f] = rdB(buf, 0, f, 0);
    if (stg) { stA(nbf, k1, 0); stA(nbf, k1, 1); }
    if (stg) asm volatile("s_waitcnt vmcnt(2)" ::: "memory");
    else     asm volatile("s_waitcnt vmcnt(0)" ::: "memory");
    GBAR();
    asm volatile("s_waitcnt lgkmcnt(0)" ::: "memory");
    __builtin_amdgcn_sched_barrier(0);
    __builtin_amdgcn_s_setprio(1);
#pragma unroll
    for (int m = 0; m < NM; m++)
#pragma unroll
      for (int f = 0; f < 4; f++)
        acc[m][f] = __builtin_amdgcn_mfma_f32_16x16x32_bf16(a[m], b[f], acc[m][f], 0, 0, 0);
    __builtin_amdgcn_s_setprio(0);
    GBAR();

    // ---------- phase 1 ----------
#pragma unroll
    for (int f = 0; f < 4; f++) b[f] = rdB(buf, 1, f, 0);
    if (stg) {
      if (BM == 256) { stA(nbf, k1, 2); stA(nbf, k1, 3); }
      else           { stB(nbf, k1, 0); stB(nbf, k1, 2); }
    }
    GBAR();
    asm volatile("s_waitcnt lgkmcnt(0)" ::: "memory");
    __builtin_amdgcn_sched_barrier(0);
    __builtin_amdgcn_s_setprio(1);
#pragma unroll
    for (int m = 0; m < NM; m++)
#pragma unroll
      for (int f = 0; f < 4; f++)
        acc[m][4 + f] = __builtin_amdgcn_mfma_f32_16x16x32_bf16(a[m], b[f], acc[m][4 + f], 0, 0, 0);
    __builtin_amdgcn_s_setprio(0);
    GBAR();

    // ---------- phase 2 ----------
#pragma unroll
    for (int m = 0; m < NM; m++) a[m] = rdA(buf, m, 1);
#pragma unroll
    for (int f = 0; f < 4; f++) b[f] = rdB(buf, 0, f, 1);
    if (stg) {
      if (BM == 256) { stB(nbf, k1, 0); stB(nbf, k1, 2); }
      else           { stB(nbf, k1, 1); stB(nbf, k1, 3); }
    }
    GBAR();
    asm volatile("s_waitcnt lgkmcnt(0)" ::: "memory");
    __builtin_amdgcn_sched_barrier(0);
    __builtin_amdgcn_s_setprio(1);
#pragma unroll
    for (int m = 0; m < NM; m++)
#pragma unroll
      for (int f = 0; f < 4; f++)
        acc[m][f] = __builtin_amdgcn_mfma_f32_16x16x32_bf16(a[m], b[f], acc[m][f], 0, 0, 0);
    __builtin_amdgcn_s_setprio(0);
    GBAR();

    // ---------- phase 3 ----------
#pragma unroll
    for (int f = 0; f < 4; f++) b[f] = rdB(buf, 1, f, 1);
    if (stg && BM == 256) { stB(nbf, k1, 1); stB(nbf, k1, 3); }
    if (stg) asm volatile("s_waitcnt vmcnt(2)" ::: "memory");
    GBAR();
    asm volatile("s_waitcnt lgkmcnt(0)" ::: "memory");
    __builtin_amdgcn_sched_barrier(0);
    __builtin_amdgcn_s_setprio(1);
#pragma unroll
    for (int m = 0; m < NM; m++)
#pragma unroll
      for (int f = 0; f < 4; f++)
        acc[m][4 + f] = __builtin_amdgcn_mfma_f32_16x16x32_bf16(a[m], b[f], acc[m][4 + f], 0, 0, 0);
    __builtin_amdgcn_s_setprio(0);
    GBAR();
  }

  if (EPI == 0) {
#pragma unroll
    for (int m = 0; m < NM; m++) {
      const int grow = bm * BM + wr * (BM / 4) + m * 16 + l4 * 4;
#pragma unroll
      for (int ni = 0; ni < 8; ni++) {
        const int col = bn * 256 + wc * 128 + (ni >> 2) * 64 + (ni & 3) * 16 + l15;
#pragma unroll
        for (int r = 0; r < 4; r++)
          C[(size_t)(grow + r) * N + col] = acc[m][ni][r];
      }
    }
  } else {
    const int head = bn * 2 + wc;
#pragma unroll
    for (int m = 0; m < NM; m++) {
#pragma unroll
      for (int r = 0; r < 4; r++) {
        const int grow = bm * BM + wr * (BM / 4) + m * 16 + l4 * 4 + r;
        const int bb = grow >> 11, pos = grow & 2047;
        if (head < 20) {
          float c4[4], s4[4];
#pragma unroll
          for (int ni = 0; ni < 4; ni++) {
            const int dh = ni * 16 + l15;
            c4[ni] = cosT[pos * 128 + dh];
            s4[ni] = sinT[pos * 128 + dh];
          }
          short* dst;
          if (head < 16) dst = Qo + ((size_t)(bb * 16 + head) * 2048 + pos) * 128;
          else           dst = Ko + ((size_t)(bb * 4 + (head - 16)) * 2048 + pos) * 128;
#pragma unroll
          for (int ni = 0; ni < 4; ni++) {
            const int dh = ni * 16 + l15;
            float xlo = acc[m][ni][r], xhi = acc[m][ni + 4][r];
            dst[dh]      = (short)f2bf(xlo * c4[ni] - xhi * s4[ni]);
            dst[dh + 64] = (short)f2bf(xhi * c4[ni] + xlo * s4[ni]);
          }
        } else {
          short* dst = Vo + ((size_t)(bb * 4 + (head - 20)) * 2048 + pos) * 128;
#pragma unroll
          for (int ni = 0; ni < 8; ni++)
            dst[(ni >> 2) * 64 + (ni & 3) * 16 + l15] = (short)f2bf(acc[m][ni][r]);
        }
      }
    }
  }
}

// ---------------- out-proj GEMM: BM=BN=128, 64KB LDS -> 2 blocks/CU ---------
// FIXED vs r14: nh is the OUTER B split (row = nh*64 + wc*32 + ...), so phase
// nh reads exactly staged half Bh_nh for ALL waves — the ledger's in-flight
// Bh1 is never read at p0/p1. Ledger: p0 stage Bh0(T+1); p1 stage A0(T+1),
// vmcnt(2) [completes Bh1(T) before its first read at p2]; p2 stage A1(T+1);
// p3 stage Bh1(T+1), vmcnt(1) [completes Bh0/A0/A1(T+1) for T+1 p0, leaves
// Bh1(T+1) in flight]. Last tile clamps vmcnt(0) at p1/p3.
__global__ __launch_bounds__(512, 2) void gemm_op(
    const short* __restrict__ A, const short* __restrict__ Bt,
    float* __restrict__ C) {
  __shared__ __align__(16) short As[2][128 * 64];
  __shared__ __align__(16) short Bs[2][128 * 64];
  const int tid = threadIdx.x;
  const int l = tid & 63, l15 = l & 15, l4 = l >> 4;
  const int wid = tid >> 6, wr = wid >> 1, wc = wid & 1;
  const int sid = (blockIdx.x & 7) * 64 + (blockIdx.x >> 3);  // XCD swizzle, 512%8==0
  const int bm = sid & 31, bn = sid >> 5;                     // 32 x 16
  const int srow = tid >> 3;      // 0..63
  const int sch = tid & 7;

  auto stA = [&](int dbuf, int k0, int i) {
    const int rl = i * 64 + srow;
    const int c = sch ^ (rl & 7);
    lds_cp16(A + (size_t)(bm * 128 + rl) * 2048 + k0 + c * 8,
             (char*)As[dbuf] + i * 8192 + tid * 16);
  };
  auto stB = [&](int dbuf, int k0, int j) {
    const int rl = j * 64 + srow;
    const int c = sch ^ (rl & 7);
    lds_cp16(Bt + (size_t)(bn * 128 + rl) * 2048 + k0 + c * 8,
             (char*)Bs[dbuf] + j * 8192 + tid * 16);
  };
  auto rdA = [&](int dbuf, int m, int kb) {
    const int row = wr * 32 + m * 16 + l15;
    return *(const bf16x8*)((const char*)As[dbuf] + (row << 7) +
                            ((kb * 64 + l4 * 16) ^ ((row & 7) << 4)));
  };
  auto rdB = [&](int dbuf, int nh, int f, int kb) {
    const int row = nh * 64 + wc * 32 + f * 16 + l15;   // nh OUTER: phase==half
    return *(const bf16x8*)((const char*)Bs[dbuf] + (row << 7) +
                            ((kb * 64 + l4 * 16) ^ ((row & 7) << 4)));
  };

  f32x4 acc[2][4];
#pragma unroll
  for (int m = 0; m < 2; m++)
#pragma unroll
    for (int n = 0; n < 4; n++) acc[m][n] = (f32x4){0.f, 0.f, 0.f, 0.f};

  const int NT = 32;

  // prologue: issue order Bh0, A0, A1, Bh1; wait leaves Bh1 in flight
  stB(0, 0, 0); stA(0, 0, 0); stA(0, 0, 1); stB(0, 0, 1);
  asm volatile("s_waitcnt vmcnt(1)" ::: "memory");
  GBAR();

  for (int kt = 0; kt < NT; kt++) {
    const int buf = kt & 1, nbf = buf ^ 1;
    const bool stg = (kt + 1 < NT);
    const int k1 = (kt + 1) << 6;
    bf16x8 a[2][2], b[2];

    // ---------- phase 0: nh=0, kb0 ----------
#pragma unroll
    for (int m = 0; m < 2; m++) a[m][0] = rdA(buf, m, 0);
#pragma unroll
    for (int f = 0; f < 2; f++) b[f] = rdB(buf, 0, f, 0);
    if (stg) stB(nbf, k1, 0);
    GBAR();
    asm volatile("s_waitcnt lgkmcnt(0)" ::: "memory");
    __builtin_amdgcn_sched_barrier(0);
    __builtin_amdgcn_s_setprio(1);
#pragma unroll
    for (int m = 0; m < 2; m++)
#pragma unroll
      for (int f = 0; f < 2; f++)
        acc[m][f] = __builtin_amdgcn_mfma_f32_16x16x32_bf16(a[m][0], b[f], acc[m][f], 0, 0, 0);
    __builtin_amdgcn_s_setprio(0);
    GBAR();

    // ---------- phase 1: nh=0, kb1 ----------
#pragma unroll
    for (int m = 0; m < 2; m++) a[m][1] = rdA(buf, m, 1);
#pragma unroll
    for (int f = 0; f < 2; f++) b[f] = rdB(buf, 0, f, 1);
    if (stg) stA(nbf, k1, 0);
    if (stg) asm volatile("s_waitcnt vmcnt(2)" ::: "memory");
    else     asm volatile("s_waitcnt vmcnt(0)" ::: "memory");
    GBAR();
    asm volatile("s_waitcnt lgkmcnt(0)" ::: "memory");
    __builtin_amdgcn_sched_barrier(0);
    __builtin_amdgcn_s_setprio(1);
#pragma unroll
    for (int m = 0; m < 2; m++)
#pragma unroll
      for (int f = 0; f < 2; f++)
        acc[m][f] = __builtin_amdgcn_mfma_f32_16x16x32_bf16(a[m][1], b[f], acc[m][f], 0, 0, 0);
    __builtin_amdgcn_s_setprio(0);
    GBAR();

    // ---------- phase 2: nh=1, kb0 ----------
#pragma unroll
    for (int f = 0; f < 2; f++) b[f] = rdB(buf, 1, f, 0);
    if (stg) stA(nbf, k1, 1);
    GBAR();
    asm volatile("s_waitcnt lgkmcnt(0)" ::: "memory");
    __builtin_amdgcn_sched_barrier(0);
    __builtin_amdgcn_s_setprio(1);
#pragma unroll
    for (int m = 0; m < 2; m++)
#pragma unroll
      for (int f = 0; f < 2; f++)
        acc[m][2 + f] = __builtin_amdgcn_mfma_f32_16x16x32_bf16(a[m][0], b[f], acc[m][2 + f], 0, 0, 0);
    __builtin_amdgcn_s_setprio(0);
    GBAR();

    // ---------- phase 3: nh=1, kb1 ----------
#pragma unroll
    for (int f = 0; f < 2; f++) b[f] = rdB(buf, 1, f, 1);
    if (stg) stB(nbf, k1, 1);
    if (stg) asm volatile("s_waitcnt vmcnt(1)" ::: "memory");
    else     asm volatile("s_waitcnt vmcnt(0)" ::: "memory");
    GBAR();
    asm volatile("s_waitcnt lgkmcnt(0)" ::: "memory");
    __builtin_amdgcn_sched_barrier(0);
    __builtin_amdgcn_s_setprio(1);
#pragma unroll
    for (int m = 0; m < 2; m++)
#pragma unroll
      for (int f = 0; f < 2; f++)
        acc[m][2 + f] = __builtin_amdgcn_mfma_f32_16x16x32_bf16(a[m][1], b[f], acc[m][2 + f], 0, 0, 0);
    __builtin_amdgcn_s_setprio(0);
    GBAR();
  }

  // epilogue: n = nh*2+f -> col = bn*128 + (n>>1)*64 + wc*32 + (n&1)*16 + l15
#pragma unroll
  for (int m = 0; m < 2; m++) {
    const int grow = bm * 128 + wr * 32 + m * 16 + l4 * 4;
#pragma unroll
    for (int n = 0; n < 4; n++) {
      const int col = bn * 128 + (n >> 1) * 64 + wc * 32 + (n & 1) * 16 + l15;
#pragma unroll
      for (int r = 0; r < 4; r++)
        C[(size_t)(grow + r) * 2048 + col] = acc[m][n][r];
    }
  }
}

// ---------------- flash attention, causal, GQA (round-10 verified) ----------
__global__ __launch_bounds__(256) void attn_fwd(
    const short* __restrict__ Q, const short* __restrict__ K,
    const short* __restrict__ VT, short* __restrict__ AO) {
  __shared__ __align__(16) short Ks[2][64 * 128];
  __shared__ __align__(16) short VTs[2][128 * 64];
  __shared__ __align__(16) short Pl[4][16 * 64];
  const int tid = threadIdx.x;
  const int w = tid >> 6, l = tid & 63;
  const int l15 = l & 15, l4 = l >> 4;
  const int bid = blockIdx.x;
  const int lg = (bid & 7) * 64 + (bid >> 3);
  const int bh = lg >> 4, pp = lg & 15;
  const int b = bh >> 4, h = bh & 15, kv = h >> 2;
  const short* Qbase = Q + (size_t)(b * 16 + h) * 2048 * 128;
  const short* Kbase = K + (size_t)(b * 4 + kv) * 2048 * 128;
  const short* VTb   = VT + (size_t)(b * 4 + kv) * 2048 * 128;

  int rk[4], ck[4], dv[4], kc[4];
#pragma unroll
  for (int i = 0; i < 4; i++) {
    const int c = tid + i * 256;
    rk[i] = c >> 4; ck[i] = (c & 15) ^ (rk[i] & 7);
    dv[i] = c >> 3; kc[i] = (c & 7) ^ (dv[i] & 7);
  }

  const float SCL = 0.08838834764831845f * 1.4426950408889634f;

  bf16x8 ones;
#pragma unroll
  for (int j = 0; j < 8; j++) ones[j] = (short)0x3F80;

  for (int qq = 0; qq < 2; qq++) {
    const int qt = qq ? (31 - pp) : pp;
    const int q0w = qt * 64 + w * 16;

    bf16x8 qf[4];
#pragma unroll
    for (int kb = 0; kb < 4; kb++)
      qf[kb] = *(const bf16x8*)(Qbase + (size_t)(q0w + l15) * 128 + kb * 32 + l4 * 8);

    f32x4 oacc[8];
#pragma unroll
    for (int i = 0; i < 8; i++) oacc[i] = (f32x4){0.f, 0.f, 0.f, 0.f};
    f32x4 lacc = (f32x4){0.f, 0.f, 0.f, 0.f};

    const int ntiles = qt + 1;

    __syncthreads();
#pragma unroll
    for (int i = 0; i < 4; i++) {
      lds_cp16(Kbase + rk[i] * 128 + ck[i] * 8, (char*)Ks[0] + i * 4096 + tid * 16);
      lds_cp16(VTb + (size_t)dv[i] * 2048 + kc[i] * 8, (char*)VTs[0] + i * 4096 + tid * 16);
    }

    for (int nt = 0; nt < ntiles; nt++) {
      const int k0 = nt * 64, buf = nt & 1;
      __syncthreads();
      if (nt + 1 < ntiles) {
        const int kn = k0 + 64, bnx = buf ^ 1;
#pragma unroll
        for (int i = 0; i < 4; i++) {
          lds_cp16(Kbase + (size_t)(kn + rk[i]) * 128 + ck[i] * 8,
                   (char*)Ks[bnx] + i * 4096 + tid * 16);
          lds_cp16(VTb + (size_t)dv[i] * 2048 + kn + kc[i] * 8,
                   (char*)VTs[bnx] + i * 4096 + tid * 16);
        }
      }

      f32x4 sa[4];
#pragma unroll
      for (int kg = 0; kg < 4; kg++) sa[kg] = (f32x4){0.f, 0.f, 0.f, 0.f};
      __builtin_amdgcn_s_setprio(1);
#pragma unroll
      for (int kg = 0; kg < 4; kg++) {
        const int row = kg * 16 + l15;
        const int swz = (row & 7) << 4;
#pragma unroll
        for (int kb = 0; kb < 4; kb++) {
          const char* kp = (const char*)Ks[buf] + row * 256 + ((kb * 64 + l4 * 16) ^ swz);
          sa[kg] = __builtin_amdgcn_mfma_f32_16x16x32_bf16(qf[kb], *(const bf16x8*)kp, sa[kg], 0, 0, 0);
        }
      }
      __builtin_amdgcn_s_setprio(0);

      float p[4][4];
      const bool domask = (k0 + 63 > q0w);
#pragma unroll
      for (int kg = 0; kg < 4; kg++)
#pragma unroll
        for (int r = 0; r < 4; r++) {
          float pv = exp2f(sa[kg][r] * SCL);
          if (domask) {
            int qrow = q0w + l4 * 4 + r;
            if (k0 + kg * 16 + l15 > qrow) pv = 0.f;
          }
          p[kg][r] = pv;
        }

#pragma unroll
      for (int r = 0; r < 4; r++) {
        const int rw = l4 * 4 + r;
        const int swz = (rw & 7) << 4;
#pragma unroll
        for (int kg = 0; kg < 4; kg++)
          *(short*)((char*)Pl[w] + (rw * 128 + ((kg * 32 + l15 * 2) ^ swz))) =
              f2bf_hw(p[kg][r]);
      }
      asm volatile("s_waitcnt lgkmcnt(0)" ::: "memory");
      bf16x8 pf[2];
#pragma unroll
      for (int ks = 0; ks < 2; ks++)
        pf[ks] = *(const bf16x8*)((const char*)Pl[w] +
                 (l15 * 128 + ((ks * 64 + l4 * 16) ^ ((l15 & 7) << 4))));

      __builtin_amdgcn_s_setprio(1);
#pragma unroll
      for (int nb = 0; nb < 8; nb++) {
        const int d = nb * 16 + l15;
        const int dsw = (d & 7) << 4;
#pragma unroll
        for (int ks = 0; ks < 2; ks++) {
          const char* vp = (const char*)VTs[buf] + d * 128 + ((ks * 64 + l4 * 16) ^ dsw);
          oacc[nb] = __builtin_amdgcn_mfma_f32_16x16x32_bf16(pf[ks], *(const bf16x8*)vp, oacc[nb], 0, 0, 0);
        }
      }
      lacc = __builtin_amdgcn_mfma_f32_16x16x32_bf16(pf[0], ones, lacc, 0, 0, 0);
      lacc = __builtin_amdgcn_mfma_f32_16x16x32_bf16(pf[1], ones, lacc, 0, 0, 0);
      __builtin_amdgcn_s_setprio(0);
    }

#pragma unroll
    for (int r = 0; r < 4; r++) {
      float inv = 1.0f / lacc[r];
      size_t rowb = ((size_t)b * 2048 + q0w + l4 * 4 + r) * 2048 + h * 128;
#pragma unroll
      for (int nb = 0; nb < 8; nb++)
        AO[rowb + nb * 16 + l15] = f2bf_hw(oacc[nb][r] * inv);
    }
  }
}

extern "C" void kernel_launch(void* const* d_in, const int* in_sizes, int n_in,
                              void* d_out, int out_size, void* d_ws, size_t ws_size,
                              hipStream_t stream) {
  const float* hs   = (const float*)d_in[0];
  const float* cosT = (const float*)d_in[1];
  const float* sinT = (const float*)d_in[2];
  const float* Wq   = (const float*)d_in[3];
  const float* Wk   = (const float*)d_in[4];
  const float* Wv   = (const float*)d_in[5];
  const float* Wo   = (const float*)d_in[6];
  float* out = (float*)d_out;

  char* p = (char*)d_ws;
  short* Xb   = (short*)p; p += (size_t)4096 * 2048 * 2;   // reused as AO
  short* Wqkv = (short*)p; p += (size_t)3072 * 2048 * 2;
  short* Wot  = (short*)p; p += (size_t)2048 * 2048 * 2;
  short* Qb   = (short*)p; p += (size_t)2 * 16 * 2048 * 128 * 2;
  short* Kb   = (short*)p; p += (size_t)2 * 4 * 2048 * 128 * 2;
  short* Vb   = (short*)p; p += (size_t)2 * 4 * 2048 * 128 * 2;
  short* VTb  = (short*)p; p += (size_t)2 * 4 * 2048 * 128 * 2;
  short* AO   = Xb;

  cast_x<<<8192, 256, 0, stream>>>(hs, Xb, 2097152);
  transp_w<<<dim3(160, 64), dim3(32, 8), 0, stream>>>(Wq, Wk, Wv, Wo, Wqkv, Wot);

  // QKV: M=4096, N=3072 -> 192 blocks, fused RoPE epilogue
  gemm8p<256, 1><<<192, 512, 0, stream>>>(Xb, Wqkv, nullptr, Qb, Kb, Vb,
                                          cosT, sinT, 3072, 2048, 16);
  transp_v<<<dim3(64, 4, 8), dim3(32, 8), 0, stream>>>(Vb, VTb);
  attn_fwd<<<512, 256, 0, stream>>>(Qb, Kb, VTb, AO);
  // out-proj: M=4096, N=2048 -> 512 blocks (2/CU, 64KB LDS)
  gemm_op<<<512, 512, 0, stream>>>(AO, Wot, out);
}